// Round 1
// baseline (2139.403 us; speedup 1.0000x reference)
//
#include <hip/hip_runtime.h>
#include <math.h>

#define B_ 8
#define T_ 2048
#define HID_ 256
#define DIN_ 512
#define NST_ 16
#define RANK_ 16
#define NL_ 4
#define NC_ 64   // scan chunks
#define TC_ 32   // steps per chunk

__device__ __forceinline__ float silu_f(float x) { return x / (1.f + __expf(-x)); }
__device__ __forceinline__ float softplus_f(float x) { return (x > 20.f) ? x : log1pf(__expf(x)); }

// -------------------- embed + layernorm --------------------
__global__ __launch_bounds__(256) void embed_ln_k(
    const float* __restrict__ tsd, const float* __restrict__ stat, const float* __restrict__ ta,
    const float* __restrict__ tsW, const float* __restrict__ tsb,
    const float* __restrict__ t2vw, const float* __restrict__ t2vb,
    const float* __restrict__ timeW, const float* __restrict__ timeb,
    const float* __restrict__ statW, const float* __restrict__ statb,
    const float* __restrict__ lng, const float* __restrict__ lnb,
    float* __restrict__ hout)
{
  int row = blockIdx.x;            // b*T + t
  int b = row >> 11, t = row & (T_ - 1);
  int j = threadIdx.x;

  __shared__ float tvs[32];
  float tav = ta[b * T_ + t];
  if (j < 32) {
    float tv = tav * t2vw[j] + t2vb[j];
    tvs[j] = (j == 0) ? tv : sinf(tv);
  }
  __syncthreads();

  float acc = tsb[j] + timeb[j] + statb[j];
  const float* tsd_bt = tsd + (size_t)b * 37 * T_ + t;
  const float* wrow = tsW + j * 37;
  #pragma unroll
  for (int m = 0; m < 37; m++) acc += tsd_bt[(size_t)m * T_] * wrow[m];
  const float* tw = timeW + j * 32;
  #pragma unroll
  for (int e = 0; e < 32; e++) acc += tvs[e] * tw[e];
  const float* sw = statW + j * 8;
  #pragma unroll
  for (int s = 0; s < 8; s++) acc += stat[b * 8 + s] * sw[s];

  // layernorm over 256
  float a = acc, q = acc * acc;
  #pragma unroll
  for (int o = 32; o > 0; o >>= 1) { a += __shfl_down(a, o, 64); q += __shfl_down(q, o, 64); }
  __shared__ float sa[4], sq[4];
  if ((threadIdx.x & 63) == 0) { sa[threadIdx.x >> 6] = a; sq[threadIdx.x >> 6] = q; }
  __syncthreads();
  float sum = sa[0] + sa[1] + sa[2] + sa[3];
  float ssq = sq[0] + sq[1] + sq[2] + sq[3];
  float mu = sum * (1.f / 256.f);
  float var = ssq * (1.f / 256.f) - mu * mu;
  hout[(size_t)row * HID_ + j] = (acc - mu) * rsqrtf(var + 1e-12f) * lng[j] + lnb[j];
}

// -------------------- rmsnorm --------------------
__global__ __launch_bounds__(256) void rmsnorm_k(
    const float* __restrict__ x, const float* __restrict__ w, float* __restrict__ o)
{
  int row = blockIdx.x, j = threadIdx.x;
  float v = x[(size_t)row * HID_ + j];
  float ss = v * v;
  #pragma unroll
  for (int ofs = 32; ofs > 0; ofs >>= 1) ss += __shfl_down(ss, ofs, 64);
  __shared__ float sb[4];
  if ((threadIdx.x & 63) == 0) sb[threadIdx.x >> 6] = ss;
  __syncthreads();
  float tot = sb[0] + sb[1] + sb[2] + sb[3];
  float sc = rsqrtf(tot * (1.f / 256.f) + 1e-5f);
  o[(size_t)row * HID_ + j] = v * sc * w[j];
}

// -------------------- generic f32 SGEMM: C[M,N] = act(A[M,lda] @ W[N,K]^T + bias) (+C) ----
template <int ACT, bool BIAS, bool RES>
__global__ __launch_bounds__(256) void sgemm_k(
    const float* __restrict__ A, int lda,
    const float* __restrict__ W,
    const float* __restrict__ bias,
    float* __restrict__ C, int ldc,
    int M, int N, int K)
{
  __shared__ float As[16][65];
  __shared__ float Ws[16][65];
  int bm = blockIdx.x * 64, bn = blockIdx.y * 64;
  int tid = threadIdx.x;
  int tx = tid & 15, ty = tid >> 4;
  int lcol = tid & 15, lrow = tid >> 4;
  float acc[4][4] = {};

  for (int k0 = 0; k0 < K; k0 += 16) {
    #pragma unroll
    for (int i = 0; i < 4; i++) {
      int m = bm + lrow + 16 * i;
      float v = 0.f;
      if (m < M && (k0 + lcol) < K) v = A[(size_t)m * lda + k0 + lcol];
      As[lcol][lrow + 16 * i] = v;
    }
    #pragma unroll
    for (int i = 0; i < 4; i++) {
      int n = bn + lrow + 16 * i;
      float v = 0.f;
      if (n < N && (k0 + lcol) < K) v = W[(size_t)n * K + k0 + lcol];
      Ws[lcol][lrow + 16 * i] = v;
    }
    __syncthreads();
    #pragma unroll
    for (int kk = 0; kk < 16; kk++) {
      float a[4], bv[4];
      #pragma unroll
      for (int r = 0; r < 4; r++) a[r] = As[kk][ty + 16 * r];
      #pragma unroll
      for (int c = 0; c < 4; c++) bv[c] = Ws[kk][tx + 16 * c];
      #pragma unroll
      for (int r = 0; r < 4; r++)
        #pragma unroll
        for (int c = 0; c < 4; c++) acc[r][c] += a[r] * bv[c];
    }
    __syncthreads();
  }

  #pragma unroll
  for (int r = 0; r < 4; r++) {
    int m = bm + ty + 16 * r;
    if (m >= M) continue;
    #pragma unroll
    for (int c = 0; c < 4; c++) {
      int n = bn + tx + 16 * c;
      if (n >= N) continue;
      float v = acc[r][c];
      if (BIAS) v += bias[n];
      if (ACT == 1) v = softplus_f(v);
      if (RES) v += C[(size_t)m * ldc + n];
      C[(size_t)m * ldc + n] = v;
    }
  }
}

// -------------------- causal depthwise conv + silu --------------------
__global__ __launch_bounds__(256) void conv_silu_k(
    const float* __restrict__ proj,   // xi in cols 0:512 of [B*T,1024]
    const float* __restrict__ cw,     // [512,4]
    const float* __restrict__ cb,     // [512]
    float* __restrict__ xc)           // [B*T,512]
{
  int idx = blockIdx.x * 256 + threadIdx.x;   // b*2^20 + t*512 + d
  int b = idx >> 20;
  int t = (idx >> 9) & (T_ - 1);
  int d = idx & (DIN_ - 1);
  float v = cb[d];
  const float* w = cw + d * 4;
  #pragma unroll
  for (int k = 0; k < 4; k++) {
    int tt = t + k - 3;
    if (tt >= 0) v += w[k] * proj[((size_t)(b * T_ + tt)) * 1024 + d];
  }
  xc[idx] = silu_f(v);
}

// -------------------- chunked selective scan --------------------
// pass A: per (b,chunk,d): running prod(dA) and local h (h_in = 0), store end-of-chunk
__global__ __launch_bounds__(512) void scan_passA_k(
    const float* __restrict__ proj,   // dt in cols 0:512
    const float* __restrict__ xc,     // u
    const float* __restrict__ xdbc,   // B at cols 16:32 of [B*T,48]
    const float* __restrict__ Alog,   // [512,16]
    float* __restrict__ chA, float* __restrict__ chH)
{
  int c = blockIdx.x, b = blockIdx.y, d = threadIdx.x;
  float a[NST_], ap[NST_], hl[NST_];
  #pragma unroll
  for (int n = 0; n < NST_; n++) {
    a[n] = -__expf(Alog[d * NST_ + n]);
    ap[n] = 1.f; hl[n] = 0.f;
  }
  __shared__ float Bs[TC_][NST_];
  {
    int st = threadIdx.x >> 4, nf = threadIdx.x & 15;
    size_t row = (size_t)(b * T_ + c * TC_ + st);
    Bs[st][nf] = xdbc[row * 48 + 16 + nf];
  }
  __syncthreads();
  size_t base = (size_t)(b * T_ + c * TC_);
  for (int s = 0; s < TC_; s++) {
    size_t row = base + s;
    float dtv = proj[row * 1024 + d];
    float u = xc[row * DIN_ + d];
    float du = dtv * u;
    #pragma unroll
    for (int n = 0; n < NST_; n++) {
      float dA = __expf(dtv * a[n]);
      ap[n] *= dA;
      hl[n] = dA * hl[n] + du * Bs[s][n];
    }
  }
  size_t o = ((size_t)((b * NC_ + c) * DIN_ + d)) * NST_;
  #pragma unroll
  for (int n = 0; n < NST_; n++) { chA[o + n] = ap[n]; chH[o + n] = hl[n]; }
}

// mid: sequential combine over chunks; overwrites chA[c] with h_in of chunk c
__global__ __launch_bounds__(256) void scan_mid_k(float* __restrict__ chA, const float* __restrict__ chH)
{
  int idx = blockIdx.x * 256 + threadIdx.x;   // over B*DIN*NST = 65536
  int b = idx >> 13;
  int dn = idx & 8191;
  float h = 0.f;
  for (int c = 0; c < NC_; c++) {
    size_t o = ((size_t)(b * NC_ + c)) * 8192 + dn;
    float ap = chA[o];
    float hl = chH[o];
    chA[o] = h;            // h_in for this chunk
    h = ap * h + hl;
  }
}

// pass C: replay chunk from true h_in, emit yz = (y + u*D) * silu(z) over dt slot
__global__ __launch_bounds__(512) void scan_passC_k(
    float* __restrict__ proj,         // dt cols 0:512 (read), z cols 512:1024 (read), write yz cols 0:512
    const float* __restrict__ xc,
    const float* __restrict__ xdbc,   // B cols 16:32, C cols 32:48
    const float* __restrict__ Alog,
    const float* __restrict__ chA,    // h_in
    const float* __restrict__ Dv)
{
  int c = blockIdx.x, b = blockIdx.y, d = threadIdx.x;
  float a[NST_], hs[NST_];
  size_t ho = ((size_t)((b * NC_ + c) * DIN_ + d)) * NST_;
  #pragma unroll
  for (int n = 0; n < NST_; n++) {
    a[n] = -__expf(Alog[d * NST_ + n]);
    hs[n] = chA[ho + n];
  }
  float dv = Dv[d];
  __shared__ float Bs[TC_][NST_], Cs[TC_][NST_];
  {
    int st = threadIdx.x >> 4, nf = threadIdx.x & 15;
    size_t row = (size_t)(b * T_ + c * TC_ + st);
    Bs[st][nf] = xdbc[row * 48 + 16 + nf];
    Cs[st][nf] = xdbc[row * 48 + 32 + nf];
  }
  __syncthreads();
  size_t base = (size_t)(b * T_ + c * TC_);
  for (int s = 0; s < TC_; s++) {
    size_t row = base + s;
    float dtv = proj[row * 1024 + d];
    float u = xc[row * DIN_ + d];
    float z = proj[row * 1024 + 512 + d];
    float du = dtv * u;
    float y = 0.f;
    #pragma unroll
    for (int n = 0; n < NST_; n++) {
      float dA = __expf(dtv * a[n]);
      hs[n] = dA * hs[n] + du * Bs[s][n];
      y += hs[n] * Cs[s][n];
    }
    y += u * dv;
    proj[row * 1024 + d] = y * silu_f(z);   // overwrite dt in place (read-before-write, thread-private)
  }
}

// -------------------- pooling + head --------------------
__global__ __launch_bounds__(256) void pool_partial_k(const float* __restrict__ xn, float* __restrict__ poolP)
{
  int b = blockIdx.x, tc = blockIdx.y, j = threadIdx.x;
  float s = 0.f;
  int t0 = tc * 256;
  #pragma unroll 4
  for (int tt = 0; tt < 256; tt++)
    s += xn[((size_t)(b * T_ + t0 + tt)) * HID_ + j];
  poolP[(b * 8 + tc) * HID_ + j] = s;
}

__global__ __launch_bounds__(256) void head_k(
    const float* __restrict__ poolP,
    const float* __restrict__ denW, const float* __restrict__ denb,
    const float* __restrict__ hdW, const float* __restrict__ hdb,
    float* __restrict__ out)
{
  int b = blockIdx.x, j = threadIdx.x;
  float p = 0.f;
  #pragma unroll
  for (int tc = 0; tc < 8; tc++) p += poolP[(b * 8 + tc) * HID_ + j];
  p *= (1.f / 2048.f);
  __shared__ float pl[256], zs[256];
  pl[j] = p;
  __syncthreads();
  float acc = denb[j];
  #pragma unroll 8
  for (int k = 0; k < 256; k++) acc += pl[k] * denW[j * 256 + k];
  zs[j] = fmaxf(acc, 0.f);
  __syncthreads();
  if (j < 2) {
    float o = hdb[j];
    for (int k = 0; k < 256; k++) o += zs[k] * hdW[j * 256 + k];
    out[b * 2 + j] = o;
  }
}

// -------------------- host --------------------
extern "C" void kernel_launch(void* const* d_in, const int* in_sizes, int n_in,
                              void* d_out, int out_size, void* d_ws, size_t ws_size,
                              hipStream_t stream)
{
  const float* tsd   = (const float*)d_in[0];
  const float* stat  = (const float*)d_in[1];
  const float* ta    = (const float*)d_in[2];
  const float* tsW   = (const float*)d_in[3];
  const float* tsb   = (const float*)d_in[4];
  const float* t2vw  = (const float*)d_in[5];
  const float* t2vb  = (const float*)d_in[6];
  const float* timeW = (const float*)d_in[7];
  const float* timeb = (const float*)d_in[8];
  const float* statW = (const float*)d_in[9];
  const float* statb = (const float*)d_in[10];
  const float* lng   = (const float*)d_in[11];
  const float* lnb   = (const float*)d_in[12];
  const float* normw = (const float*)d_in[13];
  const float* ipW   = (const float*)d_in[14];
  const float* convW = (const float*)d_in[15];
  const float* convb = (const float*)d_in[16];
  const float* xpW   = (const float*)d_in[17];
  const float* dpW   = (const float*)d_in[18];
  const float* dpb   = (const float*)d_in[19];
  const float* Alog  = (const float*)d_in[20];
  const float* Dsk   = (const float*)d_in[21];
  const float* opW   = (const float*)d_in[22];
  const float* normf = (const float*)d_in[23];
  const float* denW  = (const float*)d_in[24];
  const float* denb  = (const float*)d_in[25];
  const float* hdW   = (const float*)d_in[26];
  const float* hdb   = (const float*)d_in[27];
  float* out = (float*)d_out;

  float* ws = (float*)d_ws;
  float* h    = ws;  ws += (size_t)B_ * T_ * HID_;        // 4.19M
  float* xn   = ws;  ws += (size_t)B_ * T_ * HID_;        // 4.19M
  float* proj = ws;  ws += (size_t)B_ * T_ * 1024;        // 16.8M
  float* xc   = ws;  ws += (size_t)B_ * T_ * DIN_;        // 8.39M
  float* xdbc = ws;  ws += (size_t)B_ * T_ * 48;          // 0.79M
  float* chA  = ws;  ws += (size_t)B_ * NC_ * DIN_ * NST_; // 4.19M
  float* chH  = ws;  ws += (size_t)B_ * NC_ * DIN_ * NST_; // 4.19M
  float* poolP= ws;  ws += (size_t)B_ * 8 * HID_;

  const int ROWS = B_ * T_;   // 16384

  embed_ln_k<<<ROWS, 256, 0, stream>>>(tsd, stat, ta, tsW, tsb, t2vw, t2vb,
                                       timeW, timeb, statW, statb, lng, lnb, h);

  for (int i = 0; i < NL_; i++) {
    const float* ipWi = ipW + (size_t)i * 1024 * HID_;
    const float* xpWi = xpW + (size_t)i * 48 * DIN_;
    const float* dpWi = dpW + (size_t)i * DIN_ * RANK_;
    const float* opWi = opW + (size_t)i * HID_ * DIN_;

    rmsnorm_k<<<ROWS, 256, 0, stream>>>(h, normw + i * HID_, xn);
    // in_proj: [16384,256] @ [1024,256]^T -> proj [16384,1024]
    sgemm_k<0, false, false><<<dim3(ROWS / 64, 1024 / 64), 256, 0, stream>>>(
        xn, HID_, ipWi, nullptr, proj, 1024, ROWS, 1024, HID_);
    // causal conv + silu on xi (= proj cols 0:512)
    conv_silu_k<<<ROWS * DIN_ / 256, 256, 0, stream>>>(proj, convW + i * DIN_ * 4, convb + i * DIN_, xc);
    // x_proj: [16384,512] @ [48,512]^T -> xdbc [16384,48]
    sgemm_k<0, false, false><<<dim3(ROWS / 64, 1), 256, 0, stream>>>(
        xc, DIN_, xpWi, nullptr, xdbc, 48, ROWS, 48, DIN_);
    // dt_proj + softplus: [16384,16] @ [512,16]^T + b -> proj cols 0:512 (overwrites xi)
    sgemm_k<1, true, false><<<dim3(ROWS / 64, DIN_ / 64), 256, 0, stream>>>(
        xdbc, 48, dpWi, dpb + i * DIN_, proj, 1024, ROWS, DIN_, RANK_);
    // chunked selective scan -> yz written over dt (proj cols 0:512)
    scan_passA_k<<<dim3(NC_, B_), DIN_, 0, stream>>>(proj, xc, xdbc, Alog + i * DIN_ * NST_, chA, chH);
    scan_mid_k<<<B_ * DIN_ * NST_ / 256, 256, 0, stream>>>(chA, chH);
    scan_passC_k<<<dim3(NC_, B_), DIN_, 0, stream>>>(proj, xc, xdbc, Alog + i * DIN_ * NST_, chA, Dsk + i * DIN_);
    // out_proj + residual: [16384,512] @ [256,512]^T + h -> h
    sgemm_k<0, false, true><<<dim3(ROWS / 64, HID_ / 64), 256, 0, stream>>>(
        proj, 1024, opWi, nullptr, h, HID_, ROWS, HID_, DIN_);
  }

  rmsnorm_k<<<ROWS, 256, 0, stream>>>(h, normf, xn);
  pool_partial_k<<<dim3(B_, 8), 256, 0, stream>>>(xn, poolP);
  head_k<<<B_, 256, 0, stream>>>(poolP, denW, denb, hdW, hdb, out);
}

// Round 2
// 1284.646 us; speedup vs baseline: 1.6654x; 1.6654x over previous
//
#include <hip/hip_runtime.h>
#include <math.h>

#define B_ 8
#define T_ 2048
#define HID_ 256
#define DIN_ 512
#define NST_ 16
#define RANK_ 16
#define NL_ 4
#define NC_ 64   // scan chunks
#define TC_ 32   // steps per chunk

typedef unsigned short u16;
typedef __attribute__((ext_vector_type(8))) short bf16x8;
typedef __attribute__((ext_vector_type(4))) float f32x4;

__device__ __forceinline__ float silu_f(float x) { return x / (1.f + __expf(-x)); }
__device__ __forceinline__ float softplus_f(float x) { return (x > 20.f) ? x : log1pf(__expf(x)); }

__device__ __forceinline__ u16 f2b(float f) {
  union { float f; unsigned u; } v; v.f = f;
  unsigned r = (v.u + 0x7FFFu + ((v.u >> 16) & 1u)) >> 16;
  return (u16)r;
}
__device__ __forceinline__ float b2f(u16 b) {
  union { unsigned u; float f; } v; v.u = ((unsigned)b) << 16;
  return v.f;
}

__device__ __forceinline__ void async16(const void* g, const void* l) {
  __builtin_amdgcn_global_load_lds(
      (const __attribute__((address_space(1))) unsigned int*)g,
      (__attribute__((address_space(3))) unsigned int*)l, 16, 0, 0);
}

// -------------------- f32 -> bf16 convert --------------------
__global__ __launch_bounds__(256) void f2b_k(const float* __restrict__ s, u16* __restrict__ d, int n)
{
  int i = (blockIdx.x * 256 + threadIdx.x) * 4;
  if (i + 3 < n) {
    float4 v = *(const float4*)(s + i);
    d[i + 0] = f2b(v.x); d[i + 1] = f2b(v.y); d[i + 2] = f2b(v.z); d[i + 3] = f2b(v.w);
  } else {
    for (int k = i; k < n; k++) d[k] = f2b(s[k]);
  }
}

// -------------------- embed + layernorm --------------------
__global__ __launch_bounds__(256) void embed_ln_k(
    const float* __restrict__ tsd, const float* __restrict__ stat, const float* __restrict__ ta,
    const float* __restrict__ tsW, const float* __restrict__ tsb,
    const float* __restrict__ t2vw, const float* __restrict__ t2vb,
    const float* __restrict__ timeW, const float* __restrict__ timeb,
    const float* __restrict__ statW, const float* __restrict__ statb,
    const float* __restrict__ lng, const float* __restrict__ lnb,
    float* __restrict__ hout)
{
  int row = blockIdx.x;            // b*T + t
  int b = row >> 11, t = row & (T_ - 1);
  int j = threadIdx.x;

  __shared__ float tvs[32];
  float tav = ta[b * T_ + t];
  if (j < 32) {
    float tv = tav * t2vw[j] + t2vb[j];
    tvs[j] = (j == 0) ? tv : sinf(tv);
  }
  __syncthreads();

  float acc = tsb[j] + timeb[j] + statb[j];
  const float* tsd_bt = tsd + (size_t)b * 37 * T_ + t;
  const float* wrow = tsW + j * 37;
  #pragma unroll
  for (int m = 0; m < 37; m++) acc += tsd_bt[(size_t)m * T_] * wrow[m];
  const float* tw = timeW + j * 32;
  #pragma unroll
  for (int e = 0; e < 32; e++) acc += tvs[e] * tw[e];
  const float* sw = statW + j * 8;
  #pragma unroll
  for (int s = 0; s < 8; s++) acc += stat[b * 8 + s] * sw[s];

  float a = acc, q = acc * acc;
  #pragma unroll
  for (int o = 32; o > 0; o >>= 1) { a += __shfl_down(a, o, 64); q += __shfl_down(q, o, 64); }
  __shared__ float sa[4], sq[4];
  if ((threadIdx.x & 63) == 0) { sa[threadIdx.x >> 6] = a; sq[threadIdx.x >> 6] = q; }
  __syncthreads();
  float sum = sa[0] + sa[1] + sa[2] + sa[3];
  float ssq = sq[0] + sq[1] + sq[2] + sq[3];
  float mu = sum * (1.f / 256.f);
  float var = ssq * (1.f / 256.f) - mu * mu;
  hout[(size_t)row * HID_ + j] = (acc - mu) * rsqrtf(var + 1e-12f) * lng[j] + lnb[j];
}

// -------------------- rmsnorm (f32 in -> bf16 out) --------------------
__global__ __launch_bounds__(256) void rmsnorm_k(
    const float* __restrict__ x, const float* __restrict__ w, u16* __restrict__ o)
{
  int row = blockIdx.x, j = threadIdx.x;
  float v = x[(size_t)row * HID_ + j];
  float ss = v * v;
  #pragma unroll
  for (int ofs = 32; ofs > 0; ofs >>= 1) ss += __shfl_down(ss, ofs, 64);
  __shared__ float sb[4];
  if ((threadIdx.x & 63) == 0) sb[threadIdx.x >> 6] = ss;
  __syncthreads();
  float tot = sb[0] + sb[1] + sb[2] + sb[3];
  float sc = rsqrtf(tot * (1.f / 256.f) + 1e-5f);
  o[(size_t)row * HID_ + j] = f2b(v * sc * w[j]);
}

// -------------------- bf16 MFMA GEMM: C[M,N] = A[M,K]bf16 @ W[N,K]bf16^T (+C) ----
// 128x128 tile, BK=64, 4 waves (each 64x64), 16x16x32 MFMA, XOR-swizzled LDS.
template <bool RES>
__global__ __launch_bounds__(256) void mgemm_k(
    const u16* __restrict__ A, int lda,
    const u16* __restrict__ W, int ldw,
    float* __restrict__ C, int ldc,
    int K)
{
  __shared__ u16 sA[128 * 64];
  __shared__ u16 sB[128 * 64];
  const int tid = threadIdx.x;
  const int bm = blockIdx.x * 128, bn = blockIdx.y * 128;
  const int w = tid >> 6, l = tid & 63;
  const int wm = (w & 1) * 64, wn = (w >> 1) * 64;
  const int lr = l & 15, lh = l >> 4;

  f32x4 acc[4][4] = {};

  const int srow = tid >> 3;   // 0..31 (row within 32-row staging chunk)
  const int schunk = tid & 7;  // 16B chunk within 128B row

  for (int k0 = 0; k0 < K; k0 += 64) {
    #pragma unroll
    for (int c = 0; c < 4; c++) {
      int row = c * 32 + srow;
      int g = schunk ^ (row & 7);   // pre-swizzled global source (rule #21)
      async16(A + (size_t)(bm + row) * lda + k0 + g * 8, &sA[c * 2048 + w * 512]);
      async16(W + (size_t)(bn + row) * ldw + k0 + g * 8, &sB[c * 2048 + w * 512]);
    }
    __syncthreads();
    #pragma unroll
    for (int kk = 0; kk < 2; kk++) {
      bf16x8 af[4], bfr[4];
      #pragma unroll
      for (int i = 0; i < 4; i++) {
        int ra = wm + i * 16 + lr;
        int rb = wn + i * 16 + lr;
        int e = kk * 4 + lh;
        af[i]  = *(const bf16x8*)&sA[ra * 64 + ((e ^ (ra & 7)) * 8)];
        bfr[i] = *(const bf16x8*)&sB[rb * 64 + ((e ^ (rb & 7)) * 8)];
      }
      #pragma unroll
      for (int i = 0; i < 4; i++)
        #pragma unroll
        for (int j = 0; j < 4; j++)
          acc[i][j] = __builtin_amdgcn_mfma_f32_16x16x32_bf16(af[i], bfr[j], acc[i][j], 0, 0, 0);
    }
    __syncthreads();
  }

  #pragma unroll
  for (int i = 0; i < 4; i++) {
    int m = bm + wm + i * 16 + lh * 4;
    #pragma unroll
    for (int j = 0; j < 4; j++) {
      int n = bn + wn + j * 16 + lr;
      float* cp = C + (size_t)m * ldc + n;
      #pragma unroll
      for (int r = 0; r < 4; r++) {
        float v = acc[i][j][r];
        if (RES) v += cp[(size_t)r * ldc];
        cp[(size_t)r * ldc] = v;
      }
    }
  }
}

// -------------------- generic f32 SGEMM (x_proj, dt_proj) --------------------
template <int ACT, bool BIAS, bool RES>
__global__ __launch_bounds__(256) void sgemm_k(
    const float* __restrict__ A, int lda,
    const float* __restrict__ W,
    const float* __restrict__ bias,
    float* __restrict__ C, int ldc,
    int M, int N, int K)
{
  __shared__ float As[16][65];
  __shared__ float Ws[16][65];
  int bm = blockIdx.x * 64, bn = blockIdx.y * 64;
  int tid = threadIdx.x;
  int tx = tid & 15, ty = tid >> 4;
  int lcol = tid & 15, lrow = tid >> 4;
  float acc[4][4] = {};

  for (int k0 = 0; k0 < K; k0 += 16) {
    #pragma unroll
    for (int i = 0; i < 4; i++) {
      int m = bm + lrow + 16 * i;
      float v = 0.f;
      if (m < M && (k0 + lcol) < K) v = A[(size_t)m * lda + k0 + lcol];
      As[lcol][lrow + 16 * i] = v;
    }
    #pragma unroll
    for (int i = 0; i < 4; i++) {
      int n = bn + lrow + 16 * i;
      float v = 0.f;
      if (n < N && (k0 + lcol) < K) v = W[(size_t)n * K + k0 + lcol];
      Ws[lcol][lrow + 16 * i] = v;
    }
    __syncthreads();
    #pragma unroll
    for (int kk = 0; kk < 16; kk++) {
      float a[4], bv[4];
      #pragma unroll
      for (int r = 0; r < 4; r++) a[r] = As[kk][ty + 16 * r];
      #pragma unroll
      for (int c = 0; c < 4; c++) bv[c] = Ws[kk][tx + 16 * c];
      #pragma unroll
      for (int r = 0; r < 4; r++)
        #pragma unroll
        for (int c = 0; c < 4; c++) acc[r][c] += a[r] * bv[c];
    }
    __syncthreads();
  }

  #pragma unroll
  for (int r = 0; r < 4; r++) {
    int m = bm + ty + 16 * r;
    if (m >= M) continue;
    #pragma unroll
    for (int c = 0; c < 4; c++) {
      int n = bn + tx + 16 * c;
      if (n >= N) continue;
      float v = acc[r][c];
      if (BIAS) v += bias[n];
      if (ACT == 1) v = softplus_f(v);
      if (RES) v += C[(size_t)m * ldc + n];
      C[(size_t)m * ldc + n] = v;
    }
  }
}

// -------------------- causal depthwise conv + silu --------------------
__global__ __launch_bounds__(256) void conv_silu_k(
    const float* __restrict__ proj,   // xi in cols 0:512 of [B*T,1024]
    const float* __restrict__ cw,     // [512,4]
    const float* __restrict__ cb,     // [512]
    float* __restrict__ xc)           // [B*T,512]
{
  int idx = blockIdx.x * 256 + threadIdx.x;   // b*2^20 + t*512 + d
  int b = idx >> 20;
  int t = (idx >> 9) & (T_ - 1);
  int d = idx & (DIN_ - 1);
  float v = cb[d];
  const float* w = cw + d * 4;
  #pragma unroll
  for (int k = 0; k < 4; k++) {
    int tt = t + k - 3;
    if (tt >= 0) v += w[k] * proj[((size_t)(b * T_ + tt)) * 1024 + d];
  }
  xc[idx] = silu_f(v);
}

// -------------------- chunked selective scan --------------------
__global__ __launch_bounds__(512) void scan_passA_k(
    const float* __restrict__ proj,   // dt in cols 0:512
    const float* __restrict__ xc,     // u
    const float* __restrict__ xdbc,   // B at cols 16:32 of [B*T,48]
    const float* __restrict__ Alog,   // [512,16]
    float* __restrict__ chA, float* __restrict__ chH)
{
  int c = blockIdx.x, b = blockIdx.y, d = threadIdx.x;
  float a[NST_], ap[NST_], hl[NST_];
  #pragma unroll
  for (int n = 0; n < NST_; n++) {
    a[n] = -__expf(Alog[d * NST_ + n]);
    ap[n] = 1.f; hl[n] = 0.f;
  }
  __shared__ float Bs[TC_][NST_];
  {
    int st = threadIdx.x >> 4, nf = threadIdx.x & 15;
    size_t row = (size_t)(b * T_ + c * TC_ + st);
    Bs[st][nf] = xdbc[row * 48 + 16 + nf];
  }
  __syncthreads();
  size_t base = (size_t)(b * T_ + c * TC_);
  for (int s = 0; s < TC_; s++) {
    size_t row = base + s;
    float dtv = proj[row * 1024 + d];
    float u = xc[row * DIN_ + d];
    float du = dtv * u;
    #pragma unroll
    for (int n = 0; n < NST_; n++) {
      float dA = __expf(dtv * a[n]);
      ap[n] *= dA;
      hl[n] = dA * hl[n] + du * Bs[s][n];
    }
  }
  size_t o = ((size_t)((b * NC_ + c) * DIN_ + d)) * NST_;
  #pragma unroll
  for (int n = 0; n < NST_; n++) { chA[o + n] = ap[n]; chH[o + n] = hl[n]; }
}

__global__ __launch_bounds__(256) void scan_mid_k(float* __restrict__ chA, const float* __restrict__ chH)
{
  int idx = blockIdx.x * 256 + threadIdx.x;   // over B*DIN*NST = 65536
  int b = idx >> 13;
  int dn = idx & 8191;
  float h = 0.f;
  for (int c = 0; c < NC_; c++) {
    size_t o = ((size_t)(b * NC_ + c)) * 8192 + dn;
    float ap = chA[o];
    float hl = chH[o];
    chA[o] = h;
    h = ap * h + hl;
  }
}

// pass C: replay chunk from true h_in, emit yz = (y + u*D) * silu(z) as bf16
__global__ __launch_bounds__(512) void scan_passC_k(
    const float* __restrict__ proj,   // dt cols 0:512, z cols 512:1024
    const float* __restrict__ xc,
    const float* __restrict__ xdbc,   // B cols 16:32, C cols 32:48
    const float* __restrict__ Alog,
    const float* __restrict__ chA,    // h_in
    const float* __restrict__ Dv,
    u16* __restrict__ yzb)            // [B*T,512] bf16
{
  int c = blockIdx.x, b = blockIdx.y, d = threadIdx.x;
  float a[NST_], hs[NST_];
  size_t ho = ((size_t)((b * NC_ + c) * DIN_ + d)) * NST_;
  #pragma unroll
  for (int n = 0; n < NST_; n++) {
    a[n] = -__expf(Alog[d * NST_ + n]);
    hs[n] = chA[ho + n];
  }
  float dv = Dv[d];
  __shared__ float Bs[TC_][NST_], Cs[TC_][NST_];
  {
    int st = threadIdx.x >> 4, nf = threadIdx.x & 15;
    size_t row = (size_t)(b * T_ + c * TC_ + st);
    Bs[st][nf] = xdbc[row * 48 + 16 + nf];
    Cs[st][nf] = xdbc[row * 48 + 32 + nf];
  }
  __syncthreads();
  size_t base = (size_t)(b * T_ + c * TC_);
  for (int s = 0; s < TC_; s++) {
    size_t row = base + s;
    float dtv = proj[row * 1024 + d];
    float u = xc[row * DIN_ + d];
    float z = proj[row * 1024 + 512 + d];
    float du = dtv * u;
    float y = 0.f;
    #pragma unroll
    for (int n = 0; n < NST_; n++) {
      float dA = __expf(dtv * a[n]);
      hs[n] = dA * hs[n] + du * Bs[s][n];
      y += hs[n] * Cs[s][n];
    }
    y += u * dv;
    yzb[row * DIN_ + d] = f2b(y * silu_f(z));
  }
}

// -------------------- pooling + head --------------------
__global__ __launch_bounds__(256) void pool_partial_k(const u16* __restrict__ xn, float* __restrict__ poolP)
{
  int b = blockIdx.x, tc = blockIdx.y, j = threadIdx.x;
  float s = 0.f;
  int t0 = tc * 256;
  #pragma unroll 4
  for (int tt = 0; tt < 256; tt++)
    s += b2f(xn[((size_t)(b * T_ + t0 + tt)) * HID_ + j]);
  poolP[(b * 8 + tc) * HID_ + j] = s;
}

__global__ __launch_bounds__(256) void head_k(
    const float* __restrict__ poolP,
    const float* __restrict__ denW, const float* __restrict__ denb,
    const float* __restrict__ hdW, const float* __restrict__ hdb,
    float* __restrict__ out)
{
  int b = blockIdx.x, j = threadIdx.x;
  float p = 0.f;
  #pragma unroll
  for (int tc = 0; tc < 8; tc++) p += poolP[(b * 8 + tc) * HID_ + j];
  p *= (1.f / 2048.f);
  __shared__ float pl[256], zs[256];
  pl[j] = p;
  __syncthreads();
  float acc = denb[j];
  #pragma unroll 8
  for (int k = 0; k < 256; k++) acc += pl[k] * denW[j * 256 + k];
  zs[j] = fmaxf(acc, 0.f);
  __syncthreads();
  if (j < 2) {
    float o = hdb[j];
    for (int k = 0; k < 256; k++) o += zs[k] * hdW[j * 256 + k];
    out[b * 2 + j] = o;
  }
}

// -------------------- host --------------------
extern "C" void kernel_launch(void* const* d_in, const int* in_sizes, int n_in,
                              void* d_out, int out_size, void* d_ws, size_t ws_size,
                              hipStream_t stream)
{
  const float* tsd   = (const float*)d_in[0];
  const float* stat  = (const float*)d_in[1];
  const float* ta    = (const float*)d_in[2];
  const float* tsW   = (const float*)d_in[3];
  const float* tsb   = (const float*)d_in[4];
  const float* t2vw  = (const float*)d_in[5];
  const float* t2vb  = (const float*)d_in[6];
  const float* timeW = (const float*)d_in[7];
  const float* timeb = (const float*)d_in[8];
  const float* statW = (const float*)d_in[9];
  const float* statb = (const float*)d_in[10];
  const float* lng   = (const float*)d_in[11];
  const float* lnb   = (const float*)d_in[12];
  const float* normw = (const float*)d_in[13];
  const float* ipW   = (const float*)d_in[14];
  const float* convW = (const float*)d_in[15];
  const float* convb = (const float*)d_in[16];
  const float* xpW   = (const float*)d_in[17];
  const float* dpW   = (const float*)d_in[18];
  const float* dpb   = (const float*)d_in[19];
  const float* Alog  = (const float*)d_in[20];
  const float* Dsk   = (const float*)d_in[21];
  const float* opW   = (const float*)d_in[22];
  const float* normf = (const float*)d_in[23];
  const float* denW  = (const float*)d_in[24];
  const float* denb  = (const float*)d_in[25];
  const float* hdW   = (const float*)d_in[26];
  const float* hdb   = (const float*)d_in[27];
  float* out = (float*)d_out;

  float* ws = (float*)d_ws;
  float* h    = ws;  ws += (size_t)B_ * T_ * HID_;          // 16.8 MB
  float* proj = ws;  ws += (size_t)B_ * T_ * 1024;          // 67 MB
  float* xc   = ws;  ws += (size_t)B_ * T_ * DIN_;          // 33.5 MB
  float* xdbc = ws;  ws += (size_t)B_ * T_ * 48;            // 3.1 MB
  float* chA  = ws;  ws += (size_t)B_ * NC_ * DIN_ * NST_;  // 16.8 MB
  float* chH  = ws;  ws += (size_t)B_ * NC_ * DIN_ * NST_;  // 16.8 MB
  float* poolP= ws;  ws += (size_t)B_ * 8 * HID_;
  // bf16 region (u16), xn and yz share (disjoint lifetimes)
  u16* xnyz = (u16*)ws;  ws += (size_t)B_ * T_ * DIN_ / 2;  // 16.8 MB (8.4M u16)
  u16* wipb = (u16*)ws;  ws += (size_t)NL_ * 1024 * HID_ / 2;
  u16* wopb = (u16*)ws;  ws += (size_t)NL_ * HID_ * DIN_ / 2;

  u16* xn_b = xnyz;   // [16384, 256] bf16
  u16* yz_b = xnyz;   // [16384, 512] bf16

  const int ROWS = B_ * T_;   // 16384

  // convert weights to bf16 once per launch
  {
    int nip = NL_ * 1024 * HID_;   // 1,048,576
    int nop = NL_ * HID_ * DIN_;   // 524,288
    f2b_k<<<nip / 1024, 256, 0, stream>>>(ipW, wipb, nip);
    f2b_k<<<nop / 1024, 256, 0, stream>>>(opW, wopb, nop);
  }

  embed_ln_k<<<ROWS, 256, 0, stream>>>(tsd, stat, ta, tsW, tsb, t2vw, t2vb,
                                       timeW, timeb, statW, statb, lng, lnb, h);

  for (int i = 0; i < NL_; i++) {
    const float* xpWi = xpW + (size_t)i * 48 * DIN_;
    const float* dpWi = dpW + (size_t)i * DIN_ * RANK_;
    const u16* wipbi = wipb + (size_t)i * 1024 * HID_;
    const u16* wopbi = wopb + (size_t)i * HID_ * DIN_;

    rmsnorm_k<<<ROWS, 256, 0, stream>>>(h, normw + i * HID_, xn_b);
    // in_proj: [16384,256]bf16 @ [1024,256]bf16^T -> proj f32 [16384,1024]
    mgemm_k<false><<<dim3(ROWS / 128, 1024 / 128), 256, 0, stream>>>(
        xn_b, HID_, wipbi, HID_, proj, 1024, HID_);
    // causal conv + silu on xi (= proj cols 0:512)
    conv_silu_k<<<ROWS * DIN_ / 256, 256, 0, stream>>>(proj, convW + i * DIN_ * 4, convb + i * DIN_, xc);
    // x_proj: [16384,512] @ [48,512]^T -> xdbc [16384,48]
    sgemm_k<0, false, false><<<dim3(ROWS / 64, 1), 256, 0, stream>>>(
        xc, DIN_, xpWi, nullptr, xdbc, 48, ROWS, 48, DIN_);
    // dt_proj + softplus: [16384,16] @ [512,16]^T + b -> proj cols 0:512 (overwrites xi)
    sgemm_k<1, true, false><<<dim3(ROWS / 64, DIN_ / 64), 256, 0, stream>>>(
        xdbc, 48, dpWi, dpb + i * DIN_, proj, 1024, ROWS, DIN_, RANK_);
    // chunked selective scan -> yz bf16
    scan_passA_k<<<dim3(NC_, B_), DIN_, 0, stream>>>(proj, xc, xdbc, Alog + i * DIN_ * NST_, chA, chH);
    scan_mid_k<<<B_ * DIN_ * NST_ / 256, 256, 0, stream>>>(chA, chH);
    scan_passC_k<<<dim3(NC_, B_), DIN_, 0, stream>>>(proj, xc, xdbc, Alog + i * DIN_ * NST_, chA,
                                                     Dsk + i * DIN_, yz_b);
    // out_proj + residual: [16384,512]bf16 @ [256,512]bf16^T + h -> h
    mgemm_k<true><<<dim3(ROWS / 128, HID_ / 128), 256, 0, stream>>>(
        yz_b, DIN_, wopbi, DIN_, h, HID_, DIN_);
  }

  rmsnorm_k<<<ROWS, 256, 0, stream>>>(h, normf, xn_b);
  pool_partial_k<<<dim3(B_, 8), 256, 0, stream>>>(xn_b, poolP);
  head_k<<<B_, 256, 0, stream>>>(poolP, denW, denb, hdW, hdb, out);
}

// Round 3
// 1030.524 us; speedup vs baseline: 2.0760x; 1.2466x over previous
//
#include <hip/hip_runtime.h>
#include <math.h>

#define B_ 8
#define T_ 2048
#define HID_ 256
#define DIN_ 512
#define NST_ 16
#define RANK_ 16
#define NL_ 4
#define NC_ 64   // scan chunks
#define TC_ 32   // steps per chunk

typedef unsigned short u16;
typedef __attribute__((ext_vector_type(8))) short bf16x8;
typedef __attribute__((ext_vector_type(4))) float f32x4;

__device__ __forceinline__ float silu_f(float x) { return x / (1.f + __expf(-x)); }
__device__ __forceinline__ float softplus_f(float x) { return (x > 20.f) ? x : log1pf(__expf(x)); }

__device__ __forceinline__ u16 f2b(float f) {
  union { float f; unsigned u; } v; v.f = f;
  unsigned r = (v.u + 0x7FFFu + ((v.u >> 16) & 1u)) >> 16;
  return (u16)r;
}
__device__ __forceinline__ float b2f(u16 b) {
  union { unsigned u; float f; } v; v.u = ((unsigned)b) << 16;
  return v.f;
}

__device__ __forceinline__ void async16(const void* g, const void* l) {
  __builtin_amdgcn_global_load_lds(
      (const __attribute__((address_space(1))) unsigned int*)g,
      (__attribute__((address_space(3))) unsigned int*)l, 16, 0, 0);
}

// -------------------- f32 -> bf16 convert --------------------
__global__ __launch_bounds__(256) void f2b_k(const float* __restrict__ s, u16* __restrict__ d, int n)
{
  int i = (blockIdx.x * 256 + threadIdx.x) * 4;
  if (i + 3 < n) {
    float4 v = *(const float4*)(s + i);
    d[i + 0] = f2b(v.x); d[i + 1] = f2b(v.y); d[i + 2] = f2b(v.z); d[i + 3] = f2b(v.w);
  } else {
    for (int k = i; k < n; k++) d[k] = f2b(s[k]);
  }
}

// -------------------- embed + layernorm (register-weight, 32 rows/block) ------
__global__ __launch_bounds__(256) void embed_ln_k(
    const float* __restrict__ tsd, const float* __restrict__ stat, const float* __restrict__ ta,
    const float* __restrict__ tsW, const float* __restrict__ tsb,
    const float* __restrict__ t2vw, const float* __restrict__ t2vb,
    const float* __restrict__ timeW, const float* __restrict__ timeb,
    const float* __restrict__ statW, const float* __restrict__ statb,
    const float* __restrict__ lng, const float* __restrict__ lnb,
    float* __restrict__ hout)
{
  __shared__ float xts[37 * 32];
  __shared__ float tvs[32 * 32];
  __shared__ float outs[32 * 257];
  __shared__ float smu[32], srs[32];
  int blk = blockIdx.x;             // 512 blocks
  int b = blk >> 6, t0 = (blk & 63) * 32;
  int j = threadIdx.x;

  float wts[37], wtv[32], wst[8];
  #pragma unroll
  for (int m = 0; m < 37; m++) wts[m] = tsW[j * 37 + m];
  #pragma unroll
  for (int e = 0; e < 32; e++) wtv[e] = timeW[j * 32 + e];
  #pragma unroll
  for (int s = 0; s < 8; s++) wst[s] = statW[j * 8 + s];
  float biasj = tsb[j] + timeb[j] + statb[j];
  float lngj = lng[j], lnbj = lnb[j];
  float stq[8];
  #pragma unroll
  for (int s = 0; s < 8; s++) stq[s] = stat[b * 8 + s];

  for (int idx = j; idx < 37 * 32; idx += 256) {
    int m = idx >> 5, tt = idx & 31;
    xts[idx] = tsd[((size_t)b * 37 + m) * T_ + t0 + tt];
  }
  {
    int rr = j >> 5, ee = j & 31;
    #pragma unroll
    for (int rp = 0; rp < 4; rp++) {
      int r = rp * 8 + rr;
      float tav = ta[b * T_ + t0 + r];
      float tv = tav * t2vw[ee] + t2vb[ee];
      tvs[r * 32 + ee] = (ee == 0) ? tv : sinf(tv);
    }
  }
  __syncthreads();

  for (int r = 0; r < 32; r++) {
    float acc = biasj;
    #pragma unroll
    for (int m = 0; m < 37; m++) acc += xts[m * 32 + r] * wts[m];
    #pragma unroll
    for (int e = 0; e < 32; e++) acc += tvs[r * 32 + e] * wtv[e];
    #pragma unroll
    for (int s = 0; s < 8; s++) acc += stq[s] * wst[s];
    outs[r * 257 + j] = acc;
  }
  __syncthreads();
  {
    int r = j >> 3, q = j & 7;
    const float* po = &outs[r * 257 + q * 32];
    float s = 0.f, ss = 0.f;
    #pragma unroll
    for (int i = 0; i < 32; i++) { float v = po[i]; s += v; ss += v * v; }
    s += __shfl_down(s, 1, 64); ss += __shfl_down(ss, 1, 64);
    s += __shfl_down(s, 2, 64); ss += __shfl_down(ss, 2, 64);
    s += __shfl_down(s, 4, 64); ss += __shfl_down(ss, 4, 64);
    if (q == 0) {
      float mu = s * (1.f / 256.f);
      smu[r] = mu;
      srs[r] = rsqrtf(ss * (1.f / 256.f) - mu * mu + 1e-12f);
    }
  }
  __syncthreads();
  for (int r = 0; r < 32; r++) {
    float v = outs[r * 257 + j];
    hout[((size_t)(b * T_ + t0 + r)) * HID_ + j] = (v - smu[r]) * srs[r] * lngj + lnbj;
  }
}

// -------------------- rmsnorm (f32 in -> bf16 out) --------------------
__global__ __launch_bounds__(256) void rmsnorm_k(
    const float* __restrict__ x, const float* __restrict__ w, u16* __restrict__ o)
{
  int row = blockIdx.x, j = threadIdx.x;
  float v = x[(size_t)row * HID_ + j];
  float ss = v * v;
  #pragma unroll
  for (int ofs = 32; ofs > 0; ofs >>= 1) ss += __shfl_down(ss, ofs, 64);
  __shared__ float sb[4];
  if ((threadIdx.x & 63) == 0) sb[threadIdx.x >> 6] = ss;
  __syncthreads();
  float tot = sb[0] + sb[1] + sb[2] + sb[3];
  float sc = rsqrtf(tot * (1.f / 256.f) + 1e-5f);
  o[(size_t)row * HID_ + j] = f2b(v * sc * w[j]);
}

// -------------------- bf16 MFMA GEMM: C[M,N] = A @ W^T (+C) -----------------
// 128x128 tile, BK=64, 4 waves, 16x16x32 MFMA, XOR-swizzled LDS.
template <bool RES, bool OUTB>
__global__ __launch_bounds__(256) void mgemm_k(
    const u16* __restrict__ A, int lda,
    const u16* __restrict__ W, int ldw,
    void* __restrict__ Cv, int ldc,
    int K)
{
  __shared__ u16 sA[128 * 64];
  __shared__ u16 sB[128 * 64];
  const int tid = threadIdx.x;
  const int bm = blockIdx.x * 128, bn = blockIdx.y * 128;
  const int w = tid >> 6, l = tid & 63;
  const int wm = (w & 1) * 64, wn = (w >> 1) * 64;
  const int lr = l & 15, lh = l >> 4;

  f32x4 acc[4][4] = {};

  const int srow = tid >> 3;
  const int schunk = tid & 7;

  for (int k0 = 0; k0 < K; k0 += 64) {
    #pragma unroll
    for (int c = 0; c < 4; c++) {
      int row = c * 32 + srow;
      int g = schunk ^ (row & 7);
      async16(A + (size_t)(bm + row) * lda + k0 + g * 8, &sA[c * 2048 + w * 512]);
      async16(W + (size_t)(bn + row) * ldw + k0 + g * 8, &sB[c * 2048 + w * 512]);
    }
    __syncthreads();
    #pragma unroll
    for (int kk = 0; kk < 2; kk++) {
      bf16x8 af[4], bfr[4];
      #pragma unroll
      for (int i = 0; i < 4; i++) {
        int ra = wm + i * 16 + lr;
        int rb = wn + i * 16 + lr;
        int e = kk * 4 + lh;
        af[i]  = *(const bf16x8*)&sA[ra * 64 + ((e ^ (ra & 7)) * 8)];
        bfr[i] = *(const bf16x8*)&sB[rb * 64 + ((e ^ (rb & 7)) * 8)];
      }
      #pragma unroll
      for (int i = 0; i < 4; i++)
        #pragma unroll
        for (int j = 0; j < 4; j++)
          acc[i][j] = __builtin_amdgcn_mfma_f32_16x16x32_bf16(af[i], bfr[j], acc[i][j], 0, 0, 0);
    }
    __syncthreads();
  }

  #pragma unroll
  for (int i = 0; i < 4; i++) {
    int m = bm + wm + i * 16 + lh * 4;
    #pragma unroll
    for (int j = 0; j < 4; j++) {
      int n = bn + wn + j * 16 + lr;
      if (OUTB) {
        u16* cp = (u16*)Cv + (size_t)m * ldc + n;
        #pragma unroll
        for (int r = 0; r < 4; r++) cp[(size_t)r * ldc] = f2b(acc[i][j][r]);
      } else {
        float* cp = (float*)Cv + (size_t)m * ldc + n;
        #pragma unroll
        for (int r = 0; r < 4; r++) {
          float v = acc[i][j][r];
          if (RES) v += cp[(size_t)r * ldc];
          cp[(size_t)r * ldc] = v;
        }
      }
    }
  }
}

// -------------------- x_proj MFMA: xdbc[M,48] = xcb[M,512] @ xpW[48,512]^T ----
__global__ __launch_bounds__(256) void xproj_k(
    const u16* __restrict__ A,    // [M,512] bf16
    const u16* __restrict__ Wp,   // [48,512] bf16
    float* __restrict__ C)        // [M,48] f32
{
  __shared__ u16 sA[64 * 64];
  __shared__ u16 sW[48 * 64];
  const int tid = threadIdx.x;
  const int bm = blockIdx.x * 64;
  const int w = tid >> 6, l = tid & 63;
  const int lr = l & 15, lh = l >> 4;

  f32x4 acc[3] = {};

  for (int k0 = 0; k0 < 512; k0 += 64) {
    {
      int c = tid;
      int row = c >> 3, g = (c & 7) ^ (row & 7);
      async16(A + (size_t)(bm + row) * 512 + k0 + g * 8, &sA[(w * 64) * 8]);
      c = 256 + tid;
      row = c >> 3; g = (c & 7) ^ (row & 7);
      async16(A + (size_t)(bm + row) * 512 + k0 + g * 8, &sA[(256 + w * 64) * 8]);
    }
    {
      int c = tid;
      int row = c >> 3, g = (c & 7) ^ (row & 7);
      async16(Wp + (size_t)row * 512 + k0 + g * 8, &sW[(w * 64) * 8]);
      if (tid < 128) {
        c = 256 + tid;
        row = c >> 3; g = (c & 7) ^ (row & 7);
        async16(Wp + (size_t)row * 512 + k0 + g * 8, &sW[(256 + w * 64) * 8]);
      }
    }
    __syncthreads();
    #pragma unroll
    for (int kk = 0; kk < 2; kk++) {
      int e = kk * 4 + lh;
      int ra = w * 16 + lr;
      bf16x8 af = *(const bf16x8*)&sA[ra * 64 + ((e ^ (ra & 7)) * 8)];
      #pragma unroll
      for (int j = 0; j < 3; j++) {
        int rb = j * 16 + lr;
        bf16x8 bf = *(const bf16x8*)&sW[rb * 64 + ((e ^ (rb & 7)) * 8)];
        acc[j] = __builtin_amdgcn_mfma_f32_16x16x32_bf16(af, bf, acc[j], 0, 0, 0);
      }
    }
    __syncthreads();
  }

  int m = bm + w * 16 + lh * 4;
  #pragma unroll
  for (int j = 0; j < 3; j++) {
    int n = j * 16 + lr;
    #pragma unroll
    for (int r = 0; r < 4; r++) C[(size_t)(m + r) * 48 + n] = acc[j][r];
  }
}

// -------------------- causal depthwise conv + silu (bf16 in, dual out) -------
__global__ __launch_bounds__(256) void conv_silu_k(
    const u16* __restrict__ projb,    // xi in cols 0:512 of [B*T,1024] bf16
    const float* __restrict__ cw,     // [512,4]
    const float* __restrict__ cb,     // [512]
    float* __restrict__ xc,           // [B*T,512] f32
    u16* __restrict__ xcb)            // [B*T,512] bf16
{
  int idx = blockIdx.x * 256 + threadIdx.x;
  int b = idx >> 20;
  int t = (idx >> 9) & (T_ - 1);
  int d = idx & (DIN_ - 1);
  float v = cb[d];
  const float* w = cw + d * 4;
  #pragma unroll
  for (int k = 0; k < 4; k++) {
    int tt = t + k - 3;
    if (tt >= 0) v += w[k] * b2f(projb[((size_t)(b * T_ + tt)) * 1024 + d]);
  }
  float r = silu_f(v);
  xc[idx] = r;
  xcb[idx] = f2b(r);
}

// -------------------- chunked selective scan (dt fused) --------------------
__global__ __launch_bounds__(512) void scan_passA_k(
    const float* __restrict__ xc,
    const float* __restrict__ xdbc,   // dt-in cols 0:16, B cols 16:32
    const float* __restrict__ dpW, const float* __restrict__ dpb,
    const float* __restrict__ Alog,
    float* __restrict__ chA, float* __restrict__ chH)
{
  int c = blockIdx.x, b = blockIdx.y, d = threadIdx.x;
  float a[NST_], ap[NST_], hl[NST_], dpw[NST_];
  #pragma unroll
  for (int n = 0; n < NST_; n++) {
    a[n] = -__expf(Alog[d * NST_ + n]);
    dpw[n] = dpW[d * NST_ + n];
    ap[n] = 1.f; hl[n] = 0.f;
  }
  float dpbv = dpb[d];
  __shared__ float Ds[TC_][NST_], Bs[TC_][NST_];
  {
    int st = threadIdx.x >> 4, nf = threadIdx.x & 15;
    size_t row = (size_t)(b * T_ + c * TC_ + st);
    Ds[st][nf] = xdbc[row * 48 + nf];
    Bs[st][nf] = xdbc[row * 48 + 16 + nf];
  }
  __syncthreads();
  size_t base = (size_t)(b * T_ + c * TC_);
  for (int s = 0; s < TC_; s++) {
    size_t row = base + s;
    float u = xc[row * DIN_ + d];
    float dtr = dpbv;
    #pragma unroll
    for (int n = 0; n < NST_; n++) dtr += Ds[s][n] * dpw[n];
    float dtv = softplus_f(dtr);
    float du = dtv * u;
    #pragma unroll
    for (int n = 0; n < NST_; n++) {
      float dA = __expf(dtv * a[n]);
      ap[n] *= dA;
      hl[n] = dA * hl[n] + du * Bs[s][n];
    }
  }
  size_t o = ((size_t)((b * NC_ + c) * DIN_ + d)) * NST_;
  #pragma unroll
  for (int n = 0; n < NST_; n++) { chA[o + n] = ap[n]; chH[o + n] = hl[n]; }
}

__global__ __launch_bounds__(256) void scan_mid_k(float* __restrict__ chA, const float* __restrict__ chH)
{
  int idx = blockIdx.x * 256 + threadIdx.x;
  int b = idx >> 13;
  int dn = idx & 8191;
  float h = 0.f;
  for (int c = 0; c < NC_; c++) {
    size_t o = ((size_t)(b * NC_ + c)) * 8192 + dn;
    float ap = chA[o];
    float hl = chH[o];
    chA[o] = h;
    h = ap * h + hl;
  }
}

__global__ __launch_bounds__(512) void scan_passC_k(
    const u16* __restrict__ projb,    // z in cols 512:1024 bf16
    const float* __restrict__ xc,
    const float* __restrict__ xdbc,   // dt-in 0:16, B 16:32, C 32:48
    const float* __restrict__ dpW, const float* __restrict__ dpb,
    const float* __restrict__ Alog,
    const float* __restrict__ chA,    // h_in
    const float* __restrict__ Dv,
    u16* __restrict__ yzb)            // [B*T,512] bf16
{
  int c = blockIdx.x, b = blockIdx.y, d = threadIdx.x;
  float a[NST_], hs[NST_], dpw[NST_];
  size_t ho = ((size_t)((b * NC_ + c) * DIN_ + d)) * NST_;
  #pragma unroll
  for (int n = 0; n < NST_; n++) {
    a[n] = -__expf(Alog[d * NST_ + n]);
    dpw[n] = dpW[d * NST_ + n];
    hs[n] = chA[ho + n];
  }
  float dpbv = dpb[d];
  float dv = Dv[d];
  __shared__ float Ds[TC_][NST_], Bs[TC_][NST_], Cs[TC_][NST_];
  {
    int st = threadIdx.x >> 4, nf = threadIdx.x & 15;
    size_t row = (size_t)(b * T_ + c * TC_ + st);
    Ds[st][nf] = xdbc[row * 48 + nf];
    Bs[st][nf] = xdbc[row * 48 + 16 + nf];
    Cs[st][nf] = xdbc[row * 48 + 32 + nf];
  }
  __syncthreads();
  size_t base = (size_t)(b * T_ + c * TC_);
  for (int s = 0; s < TC_; s++) {
    size_t row = base + s;
    float u = xc[row * DIN_ + d];
    float z = b2f(projb[row * 1024 + 512 + d]);
    float dtr = dpbv;
    #pragma unroll
    for (int n = 0; n < NST_; n++) dtr += Ds[s][n] * dpw[n];
    float dtv = softplus_f(dtr);
    float du = dtv * u;
    float y = 0.f;
    #pragma unroll
    for (int n = 0; n < NST_; n++) {
      float dA = __expf(dtv * a[n]);
      hs[n] = dA * hs[n] + du * Bs[s][n];
      y += hs[n] * Cs[s][n];
    }
    y += u * dv;
    yzb[row * DIN_ + d] = f2b(y * silu_f(z));
  }
}

// -------------------- pooling + head --------------------
__global__ __launch_bounds__(256) void pool_partial_k(const u16* __restrict__ xn, float* __restrict__ poolP)
{
  int b = blockIdx.x, tc = blockIdx.y, j = threadIdx.x;
  float s = 0.f;
  int t0 = tc * 256;
  #pragma unroll 4
  for (int tt = 0; tt < 256; tt++)
    s += b2f(xn[((size_t)(b * T_ + t0 + tt)) * HID_ + j]);
  poolP[(b * 8 + tc) * HID_ + j] = s;
}

__global__ __launch_bounds__(256) void head_k(
    const float* __restrict__ poolP,
    const float* __restrict__ denW, const float* __restrict__ denb,
    const float* __restrict__ hdW, const float* __restrict__ hdb,
    float* __restrict__ out)
{
  int b = blockIdx.x, j = threadIdx.x;
  float p = 0.f;
  #pragma unroll
  for (int tc = 0; tc < 8; tc++) p += poolP[(b * 8 + tc) * HID_ + j];
  p *= (1.f / 2048.f);
  __shared__ float pl[256], zs[256];
  pl[j] = p;
  __syncthreads();
  float acc = denb[j];
  #pragma unroll 8
  for (int k = 0; k < 256; k++) acc += pl[k] * denW[j * 256 + k];
  zs[j] = fmaxf(acc, 0.f);
  __syncthreads();
  if (j < 2) {
    float o = hdb[j];
    for (int k = 0; k < 256; k++) o += zs[k] * hdW[j * 256 + k];
    out[b * 2 + j] = o;
  }
}

// -------------------- host --------------------
extern "C" void kernel_launch(void* const* d_in, const int* in_sizes, int n_in,
                              void* d_out, int out_size, void* d_ws, size_t ws_size,
                              hipStream_t stream)
{
  const float* tsd   = (const float*)d_in[0];
  const float* stat  = (const float*)d_in[1];
  const float* ta    = (const float*)d_in[2];
  const float* tsW   = (const float*)d_in[3];
  const float* tsb   = (const float*)d_in[4];
  const float* t2vw  = (const float*)d_in[5];
  const float* t2vb  = (const float*)d_in[6];
  const float* timeW = (const float*)d_in[7];
  const float* timeb = (const float*)d_in[8];
  const float* statW = (const float*)d_in[9];
  const float* statb = (const float*)d_in[10];
  const float* lng   = (const float*)d_in[11];
  const float* lnb   = (const float*)d_in[12];
  const float* normw = (const float*)d_in[13];
  const float* ipW   = (const float*)d_in[14];
  const float* convW = (const float*)d_in[15];
  const float* convb = (const float*)d_in[16];
  const float* xpW   = (const float*)d_in[17];
  const float* dpW   = (const float*)d_in[18];
  const float* dpb   = (const float*)d_in[19];
  const float* Alog  = (const float*)d_in[20];
  const float* Dsk   = (const float*)d_in[21];
  const float* opW   = (const float*)d_in[22];
  const float* normf = (const float*)d_in[23];
  const float* denW  = (const float*)d_in[24];
  const float* denb  = (const float*)d_in[25];
  const float* hdW   = (const float*)d_in[26];
  const float* hdb   = (const float*)d_in[27];
  float* out = (float*)d_out;

  float* ws = (float*)d_ws;
  float* h    = ws;  ws += (size_t)B_ * T_ * HID_;          // 16.8 MB
  float* xc   = ws;  ws += (size_t)B_ * T_ * DIN_;          // 33.5 MB
  float* xdbc = ws;  ws += (size_t)B_ * T_ * 48;            // 3.1 MB
  float* chA  = ws;  ws += (size_t)B_ * NC_ * DIN_ * NST_;  // 16.8 MB
  float* chH  = ws;  ws += (size_t)B_ * NC_ * DIN_ * NST_;  // 16.8 MB
  float* poolP= ws;  ws += (size_t)B_ * 8 * HID_;
  u16* proj_b = (u16*)ws;  ws += (size_t)B_ * T_ * 1024 / 2;  // 33.5 MB
  u16* xn_b   = (u16*)ws;  ws += (size_t)B_ * T_ * HID_ / 2;  // 8.4 MB
  u16* xcb    = (u16*)ws;  ws += (size_t)B_ * T_ * DIN_ / 2;  // 16.8 MB
  u16* yz_b   = (u16*)ws;  ws += (size_t)B_ * T_ * DIN_ / 2;  // 16.8 MB
  u16* wipb   = (u16*)ws;  ws += (size_t)NL_ * 1024 * HID_ / 2;
  u16* wopb   = (u16*)ws;  ws += (size_t)NL_ * HID_ * DIN_ / 2;
  u16* wxpb   = (u16*)ws;  ws += (size_t)NL_ * 48 * DIN_ / 2;

  const int ROWS = B_ * T_;   // 16384

  {
    int nip = NL_ * 1024 * HID_;
    int nop = NL_ * HID_ * DIN_;
    int nxp = NL_ * 48 * DIN_;
    f2b_k<<<nip / 1024, 256, 0, stream>>>(ipW, wipb, nip);
    f2b_k<<<nop / 1024, 256, 0, stream>>>(opW, wopb, nop);
    f2b_k<<<nxp / 1024, 256, 0, stream>>>(xpW, wxpb, nxp);
  }

  embed_ln_k<<<512, 256, 0, stream>>>(tsd, stat, ta, tsW, tsb, t2vw, t2vb,
                                      timeW, timeb, statW, statb, lng, lnb, h);

  for (int i = 0; i < NL_; i++) {
    const u16* wipbi = wipb + (size_t)i * 1024 * HID_;
    const u16* wopbi = wopb + (size_t)i * HID_ * DIN_;
    const u16* wxpbi = wxpb + (size_t)i * 48 * DIN_;
    const float* dpWi = dpW + (size_t)i * DIN_ * RANK_;
    const float* dpbi = dpb + (size_t)i * DIN_;
    const float* Ali  = Alog + (size_t)i * DIN_ * NST_;

    rmsnorm_k<<<ROWS, 256, 0, stream>>>(h, normw + i * HID_, xn_b);
    // in_proj -> proj_b bf16 [16384,1024]
    mgemm_k<false, true><<<dim3(ROWS / 128, 1024 / 128), 256, 0, stream>>>(
        xn_b, HID_, wipbi, HID_, proj_b, 1024, HID_);
    // conv + silu -> xc f32, xcb bf16
    conv_silu_k<<<ROWS * DIN_ / 256, 256, 0, stream>>>(proj_b, convW + i * DIN_ * 4, convb + i * DIN_, xc, xcb);
    // x_proj MFMA -> xdbc f32 [16384,48]
    xproj_k<<<ROWS / 64, 256, 0, stream>>>(xcb, wxpbi, xdbc);
    // chunked selective scan (dt fused) -> yz bf16
    scan_passA_k<<<dim3(NC_, B_), DIN_, 0, stream>>>(xc, xdbc, dpWi, dpbi, Ali, chA, chH);
    scan_mid_k<<<B_ * DIN_ * NST_ / 256, 256, 0, stream>>>(chA, chH);
    scan_passC_k<<<dim3(NC_, B_), DIN_, 0, stream>>>(proj_b, xc, xdbc, dpWi, dpbi, Ali, chA,
                                                     Dsk + i * DIN_, yz_b);
    // out_proj + residual -> h f32
    mgemm_k<true, false><<<dim3(ROWS / 128, HID_ / 128), 256, 0, stream>>>(
        yz_b, DIN_, wopbi, DIN_, h, HID_, DIN_);
  }

  rmsnorm_k<<<ROWS, 256, 0, stream>>>(h, normf, xn_b);
  pool_partial_k<<<dim3(B_, 8), 256, 0, stream>>>(xn_b, poolP);
  head_k<<<B_, 256, 0, stream>>>(poolP, denW, denb, hdW, hdb, out);
}

// Round 4
// 957.384 us; speedup vs baseline: 2.2346x; 1.0764x over previous
//
#include <hip/hip_runtime.h>
#include <math.h>

#define B_ 8
#define T_ 2048
#define HID_ 256
#define DIN_ 512
#define NST_ 16
#define RANK_ 16
#define NL_ 4
#define NC_ 64   // scan chunks
#define TC_ 32   // steps per chunk

typedef unsigned short u16;
typedef __attribute__((ext_vector_type(8))) short bf16x8;
typedef __attribute__((ext_vector_type(4))) float f32x4;

__device__ __forceinline__ float silu_f(float x) { return x / (1.f + __expf(-x)); }
__device__ __forceinline__ float softplus_f(float x) {
  return (x > 20.f) ? x : __logf(1.f + __expf(x));
}

__device__ __forceinline__ u16 f2b(float f) {
  union { float f; unsigned u; } v; v.f = f;
  unsigned r = (v.u + 0x7FFFu + ((v.u >> 16) & 1u)) >> 16;
  return (u16)r;
}
__device__ __forceinline__ float b2f(u16 b) {
  union { unsigned u; float f; } v; v.u = ((unsigned)b) << 16;
  return v.f;
}

__device__ __forceinline__ void async16(const void* g, const void* l) {
  __builtin_amdgcn_global_load_lds(
      (const __attribute__((address_space(1))) unsigned int*)g,
      (__attribute__((address_space(3))) unsigned int*)l, 16, 0, 0);
}

// -------------------- f32 -> bf16 convert --------------------
__global__ __launch_bounds__(256) void f2b_k(const float* __restrict__ s, u16* __restrict__ d, int n)
{
  int i = (blockIdx.x * 256 + threadIdx.x) * 4;
  if (i + 3 < n) {
    float4 v = *(const float4*)(s + i);
    d[i + 0] = f2b(v.x); d[i + 1] = f2b(v.y); d[i + 2] = f2b(v.z); d[i + 3] = f2b(v.w);
  } else {
    for (int k = i; k < n; k++) d[k] = f2b(s[k]);
  }
}

// -------------------- embed + layernorm (register-weight, 32 rows/block) ------
__global__ __launch_bounds__(256) void embed_ln_k(
    const float* __restrict__ tsd, const float* __restrict__ stat, const float* __restrict__ ta,
    const float* __restrict__ tsW, const float* __restrict__ tsb,
    const float* __restrict__ t2vw, const float* __restrict__ t2vb,
    const float* __restrict__ timeW, const float* __restrict__ timeb,
    const float* __restrict__ statW, const float* __restrict__ statb,
    const float* __restrict__ lng, const float* __restrict__ lnb,
    float* __restrict__ hout)
{
  __shared__ float xts[37 * 32];
  __shared__ float tvs[32 * 32];
  __shared__ float outs[32 * 257];
  __shared__ float smu[32], srs[32];
  int blk = blockIdx.x;             // 512 blocks
  int b = blk >> 6, t0 = (blk & 63) * 32;
  int j = threadIdx.x;

  float wts[37], wtv[32], wst[8];
  #pragma unroll
  for (int m = 0; m < 37; m++) wts[m] = tsW[j * 37 + m];
  #pragma unroll
  for (int e = 0; e < 32; e++) wtv[e] = timeW[j * 32 + e];
  #pragma unroll
  for (int s = 0; s < 8; s++) wst[s] = statW[j * 8 + s];
  float biasj = tsb[j] + timeb[j] + statb[j];
  float lngj = lng[j], lnbj = lnb[j];
  float stq[8];
  #pragma unroll
  for (int s = 0; s < 8; s++) stq[s] = stat[b * 8 + s];

  for (int idx = j; idx < 37 * 32; idx += 256) {
    int m = idx >> 5, tt = idx & 31;
    xts[idx] = tsd[((size_t)b * 37 + m) * T_ + t0 + tt];
  }
  {
    int rr = j >> 5, ee = j & 31;
    #pragma unroll
    for (int rp = 0; rp < 4; rp++) {
      int r = rp * 8 + rr;
      float tav = ta[b * T_ + t0 + r];
      float tv = tav * t2vw[ee] + t2vb[ee];
      tvs[r * 32 + ee] = (ee == 0) ? tv : sinf(tv);
    }
  }
  __syncthreads();

  for (int r = 0; r < 32; r++) {
    float acc = biasj;
    #pragma unroll
    for (int m = 0; m < 37; m++) acc += xts[m * 32 + r] * wts[m];
    #pragma unroll
    for (int e = 0; e < 32; e++) acc += tvs[r * 32 + e] * wtv[e];
    #pragma unroll
    for (int s = 0; s < 8; s++) acc += stq[s] * wst[s];
    outs[r * 257 + j] = acc;
  }
  __syncthreads();
  {
    int r = j >> 3, q = j & 7;
    const float* po = &outs[r * 257 + q * 32];
    float s = 0.f, ss = 0.f;
    #pragma unroll
    for (int i = 0; i < 32; i++) { float v = po[i]; s += v; ss += v * v; }
    s += __shfl_down(s, 1, 64); ss += __shfl_down(ss, 1, 64);
    s += __shfl_down(s, 2, 64); ss += __shfl_down(ss, 2, 64);
    s += __shfl_down(s, 4, 64); ss += __shfl_down(ss, 4, 64);
    if (q == 0) {
      float mu = s * (1.f / 256.f);
      smu[r] = mu;
      srs[r] = rsqrtf(ss * (1.f / 256.f) - mu * mu + 1e-12f);
    }
  }
  __syncthreads();
  for (int r = 0; r < 32; r++) {
    float v = outs[r * 257 + j];
    hout[((size_t)(b * T_ + t0 + r)) * HID_ + j] = (v - smu[r]) * srs[r] * lngj + lnbj;
  }
}

// -------------------- rmsnorm (f32 in -> bf16 out) --------------------
__global__ __launch_bounds__(256) void rmsnorm_k(
    const float* __restrict__ x, const float* __restrict__ w, u16* __restrict__ o)
{
  int row = blockIdx.x, j = threadIdx.x;
  float v = x[(size_t)row * HID_ + j];
  float ss = v * v;
  #pragma unroll
  for (int ofs = 32; ofs > 0; ofs >>= 1) ss += __shfl_down(ss, ofs, 64);
  __shared__ float sb[4];
  if ((threadIdx.x & 63) == 0) sb[threadIdx.x >> 6] = ss;
  __syncthreads();
  float tot = sb[0] + sb[1] + sb[2] + sb[3];
  float sc = rsqrtf(tot * (1.f / 256.f) + 1e-5f);
  o[(size_t)row * HID_ + j] = f2b(v * sc * w[j]);
}

// -------------------- bf16 MFMA GEMM: C[M,N] = A @ W^T (+C) -----------------
template <bool RES, bool OUTB>
__global__ __launch_bounds__(256) void mgemm_k(
    const u16* __restrict__ A, int lda,
    const u16* __restrict__ W, int ldw,
    void* __restrict__ Cv, int ldc,
    int K)
{
  __shared__ u16 sA[128 * 64];
  __shared__ u16 sB[128 * 64];
  const int tid = threadIdx.x;
  const int bm = blockIdx.x * 128, bn = blockIdx.y * 128;
  const int w = tid >> 6, l = tid & 63;
  const int wm = (w & 1) * 64, wn = (w >> 1) * 64;
  const int lr = l & 15, lh = l >> 4;

  f32x4 acc[4][4] = {};

  const int srow = tid >> 3;
  const int schunk = tid & 7;

  for (int k0 = 0; k0 < K; k0 += 64) {
    #pragma unroll
    for (int c = 0; c < 4; c++) {
      int row = c * 32 + srow;
      int g = schunk ^ (row & 7);
      async16(A + (size_t)(bm + row) * lda + k0 + g * 8, &sA[c * 2048 + w * 512]);
      async16(W + (size_t)(bn + row) * ldw + k0 + g * 8, &sB[c * 2048 + w * 512]);
    }
    __syncthreads();
    #pragma unroll
    for (int kk = 0; kk < 2; kk++) {
      bf16x8 af[4], bfr[4];
      #pragma unroll
      for (int i = 0; i < 4; i++) {
        int ra = wm + i * 16 + lr;
        int rb = wn + i * 16 + lr;
        int e = kk * 4 + lh;
        af[i]  = *(const bf16x8*)&sA[ra * 64 + ((e ^ (ra & 7)) * 8)];
        bfr[i] = *(const bf16x8*)&sB[rb * 64 + ((e ^ (rb & 7)) * 8)];
      }
      #pragma unroll
      for (int i = 0; i < 4; i++)
        #pragma unroll
        for (int j = 0; j < 4; j++)
          acc[i][j] = __builtin_amdgcn_mfma_f32_16x16x32_bf16(af[i], bfr[j], acc[i][j], 0, 0, 0);
    }
    __syncthreads();
  }

  #pragma unroll
  for (int i = 0; i < 4; i++) {
    int m = bm + wm + i * 16 + lh * 4;
    #pragma unroll
    for (int j = 0; j < 4; j++) {
      int n = bn + wn + j * 16 + lr;
      if (OUTB) {
        u16* cp = (u16*)Cv + (size_t)m * ldc + n;
        #pragma unroll
        for (int r = 0; r < 4; r++) cp[(size_t)r * ldc] = f2b(acc[i][j][r]);
      } else {
        float* cp = (float*)Cv + (size_t)m * ldc + n;
        #pragma unroll
        for (int r = 0; r < 4; r++) {
          float v = acc[i][j][r];
          if (RES) v += cp[(size_t)r * ldc];
          cp[(size_t)r * ldc] = v;
        }
      }
    }
  }
}

// -------------------- x_proj MFMA: xdbc[M,48] = xcb[M,512] @ xpW[48,512]^T ----
__global__ __launch_bounds__(256) void xproj_k(
    const u16* __restrict__ A,    // [M,512] bf16
    const u16* __restrict__ Wp,   // [48,512] bf16
    float* __restrict__ C)        // [M,48] f32
{
  __shared__ u16 sA[64 * 64];
  __shared__ u16 sW[48 * 64];
  const int tid = threadIdx.x;
  const int bm = blockIdx.x * 64;
  const int w = tid >> 6, l = tid & 63;
  const int lr = l & 15, lh = l >> 4;

  f32x4 acc[3] = {};

  for (int k0 = 0; k0 < 512; k0 += 64) {
    {
      int c = tid;
      int row = c >> 3, g = (c & 7) ^ (row & 7);
      async16(A + (size_t)(bm + row) * 512 + k0 + g * 8, &sA[(w * 64) * 8]);
      c = 256 + tid;
      row = c >> 3; g = (c & 7) ^ (row & 7);
      async16(A + (size_t)(bm + row) * 512 + k0 + g * 8, &sA[(256 + w * 64) * 8]);
    }
    {
      int c = tid;
      int row = c >> 3, g = (c & 7) ^ (row & 7);
      async16(Wp + (size_t)row * 512 + k0 + g * 8, &sW[(w * 64) * 8]);
      if (tid < 128) {
        c = 256 + tid;
        row = c >> 3; g = (c & 7) ^ (row & 7);
        async16(Wp + (size_t)row * 512 + k0 + g * 8, &sW[(256 + w * 64) * 8]);
      }
    }
    __syncthreads();
    #pragma unroll
    for (int kk = 0; kk < 2; kk++) {
      int e = kk * 4 + lh;
      int ra = w * 16 + lr;
      bf16x8 af = *(const bf16x8*)&sA[ra * 64 + ((e ^ (ra & 7)) * 8)];
      #pragma unroll
      for (int j = 0; j < 3; j++) {
        int rb = j * 16 + lr;
        bf16x8 bf = *(const bf16x8*)&sW[rb * 64 + ((e ^ (rb & 7)) * 8)];
        acc[j] = __builtin_amdgcn_mfma_f32_16x16x32_bf16(af, bf, acc[j], 0, 0, 0);
      }
    }
    __syncthreads();
  }

  int m = bm + w * 16 + lh * 4;
  #pragma unroll
  for (int j = 0; j < 3; j++) {
    int n = j * 16 + lr;
    #pragma unroll
    for (int r = 0; r < 4; r++) C[(size_t)(m + r) * 48 + n] = acc[j][r];
  }
}

// -------------------- causal depthwise conv + silu (bf16 in/out, 8 d/thread) --
__global__ __launch_bounds__(256) void conv_silu_k(
    const u16* __restrict__ projb,    // xi in cols 0:512 of [B*T,1024] bf16
    const float* __restrict__ cw,     // [512,4]
    const float* __restrict__ cb,     // [512]
    u16* __restrict__ xcb)            // [B*T,512] bf16
{
  int idx = blockIdx.x * 256 + threadIdx.x;   // ROWS*64 threads
  int row = idx >> 6;
  int t = row & (T_ - 1);
  int d0 = (idx & 63) << 3;

  float acc[8];
  *(float4*)&acc[0] = *(const float4*)&cb[d0];
  *(float4*)&acc[4] = *(const float4*)&cb[d0 + 4];
  float wreg[8][4];
  #pragma unroll
  for (int j = 0; j < 8; j++)
    *(float4*)&wreg[j][0] = *(const float4*)&cw[(d0 + j) * 4];

  #pragma unroll
  for (int k = 0; k < 4; k++) {
    int tt = t + k - 3;
    if (tt >= 0) {
      bf16x8 v = *(const bf16x8*)&projb[(size_t)(row + k - 3) * 1024 + d0];
      #pragma unroll
      for (int j = 0; j < 8; j++) acc[j] += wreg[j][k] * b2f((u16)v[j]);
    }
  }
  u16 o[8];
  #pragma unroll
  for (int j = 0; j < 8; j++) o[j] = f2b(silu_f(acc[j]));
  *(bf16x8*)&xcb[(size_t)row * 512 + d0] = *(const bf16x8*)o;
}

// -------------------- chunked selective scan (LDS-staged, dt fused) ----------
__global__ __launch_bounds__(512) void scan_passA_k(
    const u16* __restrict__ xcb,      // u bf16 [B*T,512]
    const float* __restrict__ xdbc,   // dt-in cols 0:16, B cols 16:32
    const float* __restrict__ dpW, const float* __restrict__ dpb,
    const float* __restrict__ Alog,
    float* __restrict__ chA, float* __restrict__ chH)
{
  __shared__ float sDBC[TC_ * 48];
  __shared__ u16 sU[TC_ * 512];
  int c = blockIdx.x, b = blockIdx.y, d = threadIdx.x;
  int w = d >> 6;
  size_t base_row = (size_t)(b * T_ + c * TC_);

  // stage xdbc tile: 32 rows x 48 f32 = 6 KB (contiguous), 384 threads x 16B
  if (d < 384) async16(xdbc + base_row * 48 + d * 4, &sDBC[w * 256]);
  // stage u tile: 32 rows x 512 bf16 = 32 KB (contiguous), 4 issues
  #pragma unroll
  for (int i = 0; i < 4; i++)
    async16(xcb + base_row * 512 + i * 4096 + d * 8, &sU[i * 4096 + w * 512]);

  float a2[NST_], dpw[NST_], ap[NST_], hl[NST_];
  #pragma unroll
  for (int n = 0; n < NST_; n++) {
    a2[n] = -__expf(Alog[d * NST_ + n]) * 1.44269504f;   // a * log2(e)
    dpw[n] = dpW[d * NST_ + n];
    ap[n] = 1.f; hl[n] = 0.f;
  }
  float dpbv = dpb[d];
  __syncthreads();   // waits vmcnt(0) before barrier

  for (int s = 0; s < TC_; s++) {
    const float* rowp = &sDBC[s * 48];
    float ds[16], bs[16];
    *(float4*)&ds[0]  = *(const float4*)&rowp[0];
    *(float4*)&ds[4]  = *(const float4*)&rowp[4];
    *(float4*)&ds[8]  = *(const float4*)&rowp[8];
    *(float4*)&ds[12] = *(const float4*)&rowp[12];
    *(float4*)&bs[0]  = *(const float4*)&rowp[16];
    *(float4*)&bs[4]  = *(const float4*)&rowp[20];
    *(float4*)&bs[8]  = *(const float4*)&rowp[24];
    *(float4*)&bs[12] = *(const float4*)&rowp[28];
    float dtr = dpbv;
    #pragma unroll
    for (int n = 0; n < NST_; n++) dtr += ds[n] * dpw[n];
    float dtv = softplus_f(dtr);
    float u = b2f(sU[s * 512 + d]);
    float du = dtv * u;
    #pragma unroll
    for (int n = 0; n < NST_; n++) {
      float dA = exp2f(dtv * a2[n]);
      ap[n] *= dA;
      hl[n] = dA * hl[n] + du * bs[n];
    }
  }
  size_t o = ((size_t)((b * NC_ + c) * DIN_ + d)) * NST_;
  #pragma unroll
  for (int q = 0; q < 4; q++) {
    *(float4*)&chA[o + q * 4] = *(const float4*)&ap[q * 4];
    *(float4*)&chH[o + q * 4] = *(const float4*)&hl[q * 4];
  }
}

__global__ __launch_bounds__(256) void scan_mid_k(float* __restrict__ chA, const float* __restrict__ chH)
{
  int idx = blockIdx.x * 256 + threadIdx.x;
  int b = idx >> 13;
  int dn = idx & 8191;
  float h = 0.f;
  for (int c = 0; c < NC_; c++) {
    size_t o = ((size_t)(b * NC_ + c)) * 8192 + dn;
    float ap = chA[o];
    float hl = chH[o];
    chA[o] = h;
    h = ap * h + hl;
  }
}

__global__ __launch_bounds__(512) void scan_passC_k(
    const u16* __restrict__ projb,    // z in cols 512:1024 bf16
    const u16* __restrict__ xcb,      // u bf16
    const float* __restrict__ xdbc,   // dt-in 0:16, B 16:32, C 32:48
    const float* __restrict__ dpW, const float* __restrict__ dpb,
    const float* __restrict__ Alog,
    const float* __restrict__ chA,    // h_in
    const float* __restrict__ Dv,
    u16* __restrict__ yzb)            // [B*T,512] bf16
{
  __shared__ float sDBC[TC_ * 48];
  __shared__ u16 sU[TC_ * 512];
  __shared__ u16 sZ[TC_ * 512];
  int c = blockIdx.x, b = blockIdx.y, d = threadIdx.x;
  int w = d >> 6, lane = d & 63;
  size_t base_row = (size_t)(b * T_ + c * TC_);

  if (d < 384) async16(xdbc + base_row * 48 + d * 4, &sDBC[w * 256]);
  #pragma unroll
  for (int i = 0; i < 4; i++)
    async16(xcb + base_row * 512 + i * 4096 + d * 8, &sU[i * 4096 + w * 512]);
  // z: rows not contiguous (cols 512:1024 of 1024-wide). One row per wave per issue.
  #pragma unroll
  for (int i = 0; i < 4; i++) {
    int r = i * 8 + w;
    async16(projb + (base_row + r) * 1024 + 512 + lane * 8, &sZ[r * 512]);
  }

  float a2[NST_], dpw[NST_], hs[NST_];
  size_t ho = ((size_t)((b * NC_ + c) * DIN_ + d)) * NST_;
  #pragma unroll
  for (int q = 0; q < 4; q++) *(float4*)&hs[q * 4] = *(const float4*)&chA[ho + q * 4];
  #pragma unroll
  for (int n = 0; n < NST_; n++) {
    a2[n] = -__expf(Alog[d * NST_ + n]) * 1.44269504f;
    dpw[n] = dpW[d * NST_ + n];
  }
  float dpbv = dpb[d];
  float dv = Dv[d];
  __syncthreads();

  for (int s = 0; s < TC_; s++) {
    const float* rowp = &sDBC[s * 48];
    float ds[16], bs[16], cs[16];
    *(float4*)&ds[0]  = *(const float4*)&rowp[0];
    *(float4*)&ds[4]  = *(const float4*)&rowp[4];
    *(float4*)&ds[8]  = *(const float4*)&rowp[8];
    *(float4*)&ds[12] = *(const float4*)&rowp[12];
    *(float4*)&bs[0]  = *(const float4*)&rowp[16];
    *(float4*)&bs[4]  = *(const float4*)&rowp[20];
    *(float4*)&bs[8]  = *(const float4*)&rowp[24];
    *(float4*)&bs[12] = *(const float4*)&rowp[28];
    *(float4*)&cs[0]  = *(const float4*)&rowp[32];
    *(float4*)&cs[4]  = *(const float4*)&rowp[36];
    *(float4*)&cs[8]  = *(const float4*)&rowp[40];
    *(float4*)&cs[12] = *(const float4*)&rowp[44];
    float dtr = dpbv;
    #pragma unroll
    for (int n = 0; n < NST_; n++) dtr += ds[n] * dpw[n];
    float dtv = softplus_f(dtr);
    float u = b2f(sU[s * 512 + d]);
    float z = b2f(sZ[s * 512 + d]);
    float du = dtv * u;
    float y = 0.f;
    #pragma unroll
    for (int n = 0; n < NST_; n++) {
      float dA = exp2f(dtv * a2[n]);
      hs[n] = dA * hs[n] + du * bs[n];
      y += hs[n] * cs[n];
    }
    y += u * dv;
    yzb[(base_row + s) * DIN_ + d] = f2b(y * silu_f(z));
  }
}

// -------------------- pooling + head --------------------
__global__ __launch_bounds__(256) void pool_partial_k(const u16* __restrict__ xn, float* __restrict__ poolP)
{
  int b = blockIdx.x, tc = blockIdx.y, j = threadIdx.x;
  float s = 0.f;
  int t0 = tc * 256;
  #pragma unroll 4
  for (int tt = 0; tt < 256; tt++)
    s += b2f(xn[((size_t)(b * T_ + t0 + tt)) * HID_ + j]);
  poolP[(b * 8 + tc) * HID_ + j] = s;
}

__global__ __launch_bounds__(256) void head_k(
    const float* __restrict__ poolP,
    const float* __restrict__ denW, const float* __restrict__ denb,
    const float* __restrict__ hdW, const float* __restrict__ hdb,
    float* __restrict__ out)
{
  int b = blockIdx.x, j = threadIdx.x;
  float p = 0.f;
  #pragma unroll
  for (int tc = 0; tc < 8; tc++) p += poolP[(b * 8 + tc) * HID_ + j];
  p *= (1.f / 2048.f);
  __shared__ float pl[256], zs[256];
  pl[j] = p;
  __syncthreads();
  float acc = denb[j];
  #pragma unroll 8
  for (int k = 0; k < 256; k++) acc += pl[k] * denW[j * 256 + k];
  zs[j] = fmaxf(acc, 0.f);
  __syncthreads();
  if (j < 2) {
    float o = hdb[j];
    for (int k = 0; k < 256; k++) o += zs[k] * hdW[j * 256 + k];
    out[b * 2 + j] = o;
  }
}

// -------------------- host --------------------
extern "C" void kernel_launch(void* const* d_in, const int* in_sizes, int n_in,
                              void* d_out, int out_size, void* d_ws, size_t ws_size,
                              hipStream_t stream)
{
  const float* tsd   = (const float*)d_in[0];
  const float* stat  = (const float*)d_in[1];
  const float* ta    = (const float*)d_in[2];
  const float* tsW   = (const float*)d_in[3];
  const float* tsb   = (const float*)d_in[4];
  const float* t2vw  = (const float*)d_in[5];
  const float* t2vb  = (const float*)d_in[6];
  const float* timeW = (const float*)d_in[7];
  const float* timeb = (const float*)d_in[8];
  const float* statW = (const float*)d_in[9];
  const float* statb = (const float*)d_in[10];
  const float* lng   = (const float*)d_in[11];
  const float* lnb   = (const float*)d_in[12];
  const float* normw = (const float*)d_in[13];
  const float* ipW   = (const float*)d_in[14];
  const float* convW = (const float*)d_in[15];
  const float* convb = (const float*)d_in[16];
  const float* xpW   = (const float*)d_in[17];
  const float* dpW   = (const float*)d_in[18];
  const float* dpb   = (const float*)d_in[19];
  const float* Alog  = (const float*)d_in[20];
  const float* Dsk   = (const float*)d_in[21];
  const float* opW   = (const float*)d_in[22];
  const float* normf = (const float*)d_in[23];
  const float* denW  = (const float*)d_in[24];
  const float* denb  = (const float*)d_in[25];
  const float* hdW   = (const float*)d_in[26];
  const float* hdb   = (const float*)d_in[27];
  float* out = (float*)d_out;

  float* ws = (float*)d_ws;
  float* h    = ws;  ws += (size_t)B_ * T_ * HID_;          // 16.8 MB
  float* xdbc = ws;  ws += (size_t)B_ * T_ * 48;            // 3.1 MB
  float* chA  = ws;  ws += (size_t)B_ * NC_ * DIN_ * NST_;  // 16.8 MB
  float* chH  = ws;  ws += (size_t)B_ * NC_ * DIN_ * NST_;  // 16.8 MB
  float* poolP= ws;  ws += (size_t)B_ * 8 * HID_;
  u16* proj_b = (u16*)ws;  ws += (size_t)B_ * T_ * 1024 / 2;  // 33.5 MB
  u16* xn_b   = (u16*)ws;  ws += (size_t)B_ * T_ * HID_ / 2;  // 8.4 MB
  u16* xcb    = (u16*)ws;  ws += (size_t)B_ * T_ * DIN_ / 2;  // 16.8 MB
  u16* yz_b   = (u16*)ws;  ws += (size_t)B_ * T_ * DIN_ / 2;  // 16.8 MB
  u16* wipb   = (u16*)ws;  ws += (size_t)NL_ * 1024 * HID_ / 2;
  u16* wopb   = (u16*)ws;  ws += (size_t)NL_ * HID_ * DIN_ / 2;
  u16* wxpb   = (u16*)ws;  ws += (size_t)NL_ * 48 * DIN_ / 2;

  const int ROWS = B_ * T_;   // 16384

  {
    int nip = NL_ * 1024 * HID_;
    int nop = NL_ * HID_ * DIN_;
    int nxp = NL_ * 48 * DIN_;
    f2b_k<<<nip / 1024, 256, 0, stream>>>(ipW, wipb, nip);
    f2b_k<<<nop / 1024, 256, 0, stream>>>(opW, wopb, nop);
    f2b_k<<<nxp / 1024, 256, 0, stream>>>(xpW, wxpb, nxp);
  }

  embed_ln_k<<<512, 256, 0, stream>>>(tsd, stat, ta, tsW, tsb, t2vw, t2vb,
                                      timeW, timeb, statW, statb, lng, lnb, h);

  for (int i = 0; i < NL_; i++) {
    const u16* wipbi = wipb + (size_t)i * 1024 * HID_;
    const u16* wopbi = wopb + (size_t)i * HID_ * DIN_;
    const u16* wxpbi = wxpb + (size_t)i * 48 * DIN_;
    const float* dpWi = dpW + (size_t)i * DIN_ * RANK_;
    const float* dpbi = dpb + (size_t)i * DIN_;
    const float* Ali  = Alog + (size_t)i * DIN_ * NST_;

    rmsnorm_k<<<ROWS, 256, 0, stream>>>(h, normw + i * HID_, xn_b);
    // in_proj -> proj_b bf16 [16384,1024]
    mgemm_k<false, true><<<dim3(ROWS / 128, 1024 / 128), 256, 0, stream>>>(
        xn_b, HID_, wipbi, HID_, proj_b, 1024, HID_);
    // conv + silu -> xcb bf16
    conv_silu_k<<<ROWS * 64 / 256, 256, 0, stream>>>(proj_b, convW + i * DIN_ * 4, convb + i * DIN_, xcb);
    // x_proj MFMA -> xdbc f32 [16384,48]
    xproj_k<<<ROWS / 64, 256, 0, stream>>>(xcb, wxpbi, xdbc);
    // chunked selective scan (dt fused) -> yz bf16
    scan_passA_k<<<dim3(NC_, B_), DIN_, 0, stream>>>(xcb, xdbc, dpWi, dpbi, Ali, chA, chH);
    scan_mid_k<<<B_ * DIN_ * NST_ / 256, 256, 0, stream>>>(chA, chH);
    scan_passC_k<<<dim3(NC_, B_), DIN_, 0, stream>>>(proj_b, xcb, xdbc, dpWi, dpbi, Ali, chA,
                                                     Dsk + i * DIN_, yz_b);
    // out_proj + residual -> h f32
    mgemm_k<true, false><<<dim3(ROWS / 128, HID_ / 128), 256, 0, stream>>>(
        yz_b, DIN_, wopbi, DIN_, h, HID_, DIN_);
  }

  rmsnorm_k<<<ROWS, 256, 0, stream>>>(h, normf, xn_b);
  pool_partial_k<<<dim3(B_, 8), 256, 0, stream>>>(xn_b, poolP);
  head_k<<<B_, 256, 0, stream>>>(poolP, denW, denb, hdW, hdb, out);
}

// Round 5
// 824.116 us; speedup vs baseline: 2.5960x; 1.1617x over previous
//
#include <hip/hip_runtime.h>
#include <math.h>

#define B_ 8
#define T_ 2048
#define HID_ 256
#define DIN_ 512
#define NST_ 16
#define RANK_ 16
#define NL_ 4
#define NC_ 64   // scan chunks
#define TC_ 32   // steps per chunk

typedef unsigned short u16;
typedef __attribute__((ext_vector_type(8))) short bf16x8;
typedef __attribute__((ext_vector_type(4))) float f32x4;

// single-instruction transcendentals (v_exp_f32 = 2^x)
__device__ __forceinline__ float exp2_i(float x) {
  float r; asm("v_exp_f32 %0, %1" : "=v"(r) : "v"(x)); return r;
}
__device__ __forceinline__ float log2_i(float x) {
  float r; asm("v_log_f32 %0, %1" : "=v"(r) : "v"(x)); return r;
}
__device__ __forceinline__ float rcp_i(float x) {
  float r; asm("v_rcp_f32 %0, %1" : "=v"(r) : "v"(x)); return r;
}
#define LOG2E 1.44269504f
#define LN2   0.69314718f

__device__ __forceinline__ float silu_f(float x) {
  return x * rcp_i(1.f + exp2_i(-LOG2E * x));
}
__device__ __forceinline__ float softplus_f(float x) {
  return (x > 20.f) ? x : LN2 * log2_i(1.f + exp2_i(LOG2E * x));
}

__device__ __forceinline__ u16 f2b(float f) {
  union { float f; unsigned u; } v; v.f = f;
  unsigned r = (v.u + 0x7FFFu + ((v.u >> 16) & 1u)) >> 16;
  return (u16)r;
}
__device__ __forceinline__ float b2f(u16 b) {
  union { unsigned u; float f; } v; v.u = ((unsigned)b) << 16;
  return v.f;
}

__device__ __forceinline__ void async16(const void* g, const void* l) {
  __builtin_amdgcn_global_load_lds(
      (const __attribute__((address_space(1))) unsigned int*)g,
      (__attribute__((address_space(3))) unsigned int*)l, 16, 0, 0);
}

// -------------------- f32 -> bf16 convert --------------------
__global__ __launch_bounds__(256) void f2b_k(const float* __restrict__ s, u16* __restrict__ d, int n)
{
  int i = (blockIdx.x * 256 + threadIdx.x) * 4;
  if (i + 3 < n) {
    float4 v = *(const float4*)(s + i);
    d[i + 0] = f2b(v.x); d[i + 1] = f2b(v.y); d[i + 2] = f2b(v.z); d[i + 3] = f2b(v.w);
  } else {
    for (int k = i; k < n; k++) d[k] = f2b(s[k]);
  }
}

// -------------------- embed + layernorm (register-weight, 32 rows/block) ------
__global__ __launch_bounds__(256) void embed_ln_k(
    const float* __restrict__ tsd, const float* __restrict__ stat, const float* __restrict__ ta,
    const float* __restrict__ tsW, const float* __restrict__ tsb,
    const float* __restrict__ t2vw, const float* __restrict__ t2vb,
    const float* __restrict__ timeW, const float* __restrict__ timeb,
    const float* __restrict__ statW, const float* __restrict__ statb,
    const float* __restrict__ lng, const float* __restrict__ lnb,
    float* __restrict__ hout)
{
  __shared__ float xts[37 * 32];
  __shared__ float tvs[32 * 32];
  __shared__ float outs[32 * 257];
  __shared__ float smu[32], srs[32];
  int blk = blockIdx.x;             // 512 blocks
  int b = blk >> 6, t0 = (blk & 63) * 32;
  int j = threadIdx.x;

  float wts[37], wtv[32], wst[8];
  #pragma unroll
  for (int m = 0; m < 37; m++) wts[m] = tsW[j * 37 + m];
  #pragma unroll
  for (int e = 0; e < 32; e++) wtv[e] = timeW[j * 32 + e];
  #pragma unroll
  for (int s = 0; s < 8; s++) wst[s] = statW[j * 8 + s];
  float biasj = tsb[j] + timeb[j] + statb[j];
  float lngj = lng[j], lnbj = lnb[j];
  float stq[8];
  #pragma unroll
  for (int s = 0; s < 8; s++) stq[s] = stat[b * 8 + s];

  for (int idx = j; idx < 37 * 32; idx += 256) {
    int m = idx >> 5, tt = idx & 31;
    xts[idx] = tsd[((size_t)b * 37 + m) * T_ + t0 + tt];
  }
  {
    int rr = j >> 5, ee = j & 31;
    #pragma unroll
    for (int rp = 0; rp < 4; rp++) {
      int r = rp * 8 + rr;
      float tav = ta[b * T_ + t0 + r];
      float tv = tav * t2vw[ee] + t2vb[ee];
      tvs[r * 32 + ee] = (ee == 0) ? tv : sinf(tv);
    }
  }
  __syncthreads();

  for (int r = 0; r < 32; r++) {
    float acc = biasj;
    #pragma unroll
    for (int m = 0; m < 37; m++) acc += xts[m * 32 + r] * wts[m];
    #pragma unroll
    for (int e = 0; e < 32; e++) acc += tvs[r * 32 + e] * wtv[e];
    #pragma unroll
    for (int s = 0; s < 8; s++) acc += stq[s] * wst[s];
    outs[r * 257 + j] = acc;
  }
  __syncthreads();
  {
    int r = j >> 3, q = j & 7;
    const float* po = &outs[r * 257 + q * 32];
    float s = 0.f, ss = 0.f;
    #pragma unroll
    for (int i = 0; i < 32; i++) { float v = po[i]; s += v; ss += v * v; }
    s += __shfl_down(s, 1, 64); ss += __shfl_down(ss, 1, 64);
    s += __shfl_down(s, 2, 64); ss += __shfl_down(ss, 2, 64);
    s += __shfl_down(s, 4, 64); ss += __shfl_down(ss, 4, 64);
    if (q == 0) {
      float mu = s * (1.f / 256.f);
      smu[r] = mu;
      srs[r] = rsqrtf(ss * (1.f / 256.f) - mu * mu + 1e-12f);
    }
  }
  __syncthreads();
  for (int r = 0; r < 32; r++) {
    float v = outs[r * 257 + j];
    hout[((size_t)(b * T_ + t0 + r)) * HID_ + j] = (v - smu[r]) * srs[r] * lngj + lnbj;
  }
}

// -------------------- rmsnorm (f32 in -> bf16 out) --------------------
__global__ __launch_bounds__(256) void rmsnorm_k(
    const float* __restrict__ x, const float* __restrict__ w, u16* __restrict__ o)
{
  int row = blockIdx.x, j = threadIdx.x;
  float v = x[(size_t)row * HID_ + j];
  float ss = v * v;
  #pragma unroll
  for (int ofs = 32; ofs > 0; ofs >>= 1) ss += __shfl_down(ss, ofs, 64);
  __shared__ float sb[4];
  if ((threadIdx.x & 63) == 0) sb[threadIdx.x >> 6] = ss;
  __syncthreads();
  float tot = sb[0] + sb[1] + sb[2] + sb[3];
  float sc = rsqrtf(tot * (1.f / 256.f) + 1e-5f);
  o[(size_t)row * HID_ + j] = f2b(v * sc * w[j]);
}

// -------------------- bf16 MFMA GEMM: C[M,N] = A @ W^T (+C) -----------------
template <bool RES, bool OUTB>
__global__ __launch_bounds__(256) void mgemm_k(
    const u16* __restrict__ A, int lda,
    const u16* __restrict__ W, int ldw,
    void* __restrict__ Cv, int ldc,
    int K)
{
  __shared__ u16 sA[128 * 64];
  __shared__ u16 sB[128 * 64];
  const int tid = threadIdx.x;
  const int bm = blockIdx.x * 128, bn = blockIdx.y * 128;
  const int w = tid >> 6, l = tid & 63;
  const int wm = (w & 1) * 64, wn = (w >> 1) * 64;
  const int lr = l & 15, lh = l >> 4;

  f32x4 acc[4][4] = {};

  const int srow = tid >> 3;
  const int schunk = tid & 7;

  for (int k0 = 0; k0 < K; k0 += 64) {
    #pragma unroll
    for (int c = 0; c < 4; c++) {
      int row = c * 32 + srow;
      int g = schunk ^ (row & 7);
      async16(A + (size_t)(bm + row) * lda + k0 + g * 8, &sA[c * 2048 + w * 512]);
      async16(W + (size_t)(bn + row) * ldw + k0 + g * 8, &sB[c * 2048 + w * 512]);
    }
    __syncthreads();
    #pragma unroll
    for (int kk = 0; kk < 2; kk++) {
      bf16x8 af[4], bfr[4];
      #pragma unroll
      for (int i = 0; i < 4; i++) {
        int ra = wm + i * 16 + lr;
        int rb = wn + i * 16 + lr;
        int e = kk * 4 + lh;
        af[i]  = *(const bf16x8*)&sA[ra * 64 + ((e ^ (ra & 7)) * 8)];
        bfr[i] = *(const bf16x8*)&sB[rb * 64 + ((e ^ (rb & 7)) * 8)];
      }
      #pragma unroll
      for (int i = 0; i < 4; i++)
        #pragma unroll
        for (int j = 0; j < 4; j++)
          acc[i][j] = __builtin_amdgcn_mfma_f32_16x16x32_bf16(af[i], bfr[j], acc[i][j], 0, 0, 0);
    }
    __syncthreads();
  }

  #pragma unroll
  for (int i = 0; i < 4; i++) {
    int m = bm + wm + i * 16 + lh * 4;
    #pragma unroll
    for (int j = 0; j < 4; j++) {
      int n = bn + wn + j * 16 + lr;
      if (OUTB) {
        u16* cp = (u16*)Cv + (size_t)m * ldc + n;
        #pragma unroll
        for (int r = 0; r < 4; r++) cp[(size_t)r * ldc] = f2b(acc[i][j][r]);
      } else {
        float* cp = (float*)Cv + (size_t)m * ldc + n;
        #pragma unroll
        for (int r = 0; r < 4; r++) {
          float v = acc[i][j][r];
          if (RES) v += cp[(size_t)r * ldc];
          cp[(size_t)r * ldc] = v;
        }
      }
    }
  }
}

// -------------------- x_proj MFMA: xdbc[M,48] = xcb[M,512] @ xpW[48,512]^T ----
__global__ __launch_bounds__(256) void xproj_k(
    const u16* __restrict__ A,    // [M,512] bf16
    const u16* __restrict__ Wp,   // [48,512] bf16
    float* __restrict__ C)        // [M,48] f32
{
  __shared__ u16 sA[64 * 64];
  __shared__ u16 sW[48 * 64];
  const int tid = threadIdx.x;
  const int bm = blockIdx.x * 64;
  const int w = tid >> 6, l = tid & 63;
  const int lr = l & 15, lh = l >> 4;

  f32x4 acc[3] = {};

  for (int k0 = 0; k0 < 512; k0 += 64) {
    {
      int c = tid;
      int row = c >> 3, g = (c & 7) ^ (row & 7);
      async16(A + (size_t)(bm + row) * 512 + k0 + g * 8, &sA[(w * 64) * 8]);
      c = 256 + tid;
      row = c >> 3; g = (c & 7) ^ (row & 7);
      async16(A + (size_t)(bm + row) * 512 + k0 + g * 8, &sA[(256 + w * 64) * 8]);
    }
    {
      int c = tid;
      int row = c >> 3, g = (c & 7) ^ (row & 7);
      async16(Wp + (size_t)row * 512 + k0 + g * 8, &sW[(w * 64) * 8]);
      if (tid < 128) {
        c = 256 + tid;
        row = c >> 3; g = (c & 7) ^ (row & 7);
        async16(Wp + (size_t)row * 512 + k0 + g * 8, &sW[(256 + w * 64) * 8]);
      }
    }
    __syncthreads();
    #pragma unroll
    for (int kk = 0; kk < 2; kk++) {
      int e = kk * 4 + lh;
      int ra = w * 16 + lr;
      bf16x8 af = *(const bf16x8*)&sA[ra * 64 + ((e ^ (ra & 7)) * 8)];
      #pragma unroll
      for (int j = 0; j < 3; j++) {
        int rb = j * 16 + lr;
        bf16x8 bf = *(const bf16x8*)&sW[rb * 64 + ((e ^ (rb & 7)) * 8)];
        acc[j] = __builtin_amdgcn_mfma_f32_16x16x32_bf16(af, bf, acc[j], 0, 0, 0);
      }
    }
    __syncthreads();
  }

  int m = bm + w * 16 + lh * 4;
  #pragma unroll
  for (int j = 0; j < 3; j++) {
    int n = j * 16 + lr;
    #pragma unroll
    for (int r = 0; r < 4; r++) C[(size_t)(m + r) * 48 + n] = acc[j][r];
  }
}

// -------------------- causal depthwise conv + silu (bf16 in/out, 8 d/thread) --
__global__ __launch_bounds__(256) void conv_silu_k(
    const u16* __restrict__ xib,      // [B*T,512] bf16
    const float* __restrict__ cw,     // [512,4]
    const float* __restrict__ cb,     // [512]
    u16* __restrict__ xcb)            // [B*T,512] bf16
{
  int idx = blockIdx.x * 256 + threadIdx.x;   // ROWS*64 threads
  int row = idx >> 6;
  int t = row & (T_ - 1);
  int d0 = (idx & 63) << 3;

  float acc[8];
  *(float4*)&acc[0] = *(const float4*)&cb[d0];
  *(float4*)&acc[4] = *(const float4*)&cb[d0 + 4];
  float wreg[8][4];
  #pragma unroll
  for (int j = 0; j < 8; j++)
    *(float4*)&wreg[j][0] = *(const float4*)&cw[(d0 + j) * 4];

  #pragma unroll
  for (int k = 0; k < 4; k++) {
    int tt = t + k - 3;
    if (tt >= 0) {
      bf16x8 v = *(const bf16x8*)&xib[(size_t)(row + k - 3) * 512 + d0];
      #pragma unroll
      for (int j = 0; j < 8; j++) acc[j] += wreg[j][k] * b2f((u16)v[j]);
    }
  }
  u16 o[8];
  #pragma unroll
  for (int j = 0; j < 8; j++) o[j] = f2b(silu_f(acc[j]));
  *(bf16x8*)&xcb[(size_t)row * 512 + d0] = *(const bf16x8*)o;
}

// -------------------- chunked selective scan (LDS-staged, dt fused) ----------
__global__ __launch_bounds__(512) void scan_passA_k(
    const u16* __restrict__ xcb,      // u bf16 [B*T,512]
    const float* __restrict__ xdbc,   // dt-in cols 0:16, B cols 16:32
    const float* __restrict__ dpW, const float* __restrict__ dpb,
    const float* __restrict__ Alog,
    float* __restrict__ chA, float* __restrict__ chH)
{
  __shared__ float sDBC[TC_ * 48];
  __shared__ u16 sU[TC_ * 512];
  int c = blockIdx.x, b = blockIdx.y, d = threadIdx.x;
  int w = d >> 6;
  size_t base_row = (size_t)(b * T_ + c * TC_);

  if (d < 384) async16(xdbc + base_row * 48 + d * 4, &sDBC[w * 256]);
  #pragma unroll
  for (int i = 0; i < 4; i++)
    async16(xcb + base_row * 512 + i * 4096 + d * 8, &sU[i * 4096 + w * 512]);

  float a2[NST_], dpw[NST_], ap[NST_], hl[NST_];
  #pragma unroll
  for (int n = 0; n < NST_; n++) {
    a2[n] = -exp2_i(Alog[d * NST_ + n] * LOG2E) * LOG2E;  // a*log2(e)
    dpw[n] = dpW[d * NST_ + n];
    ap[n] = 1.f; hl[n] = 0.f;
  }
  float dpbv = dpb[d];
  __syncthreads();

  for (int s = 0; s < TC_; s++) {
    const float* rowp = &sDBC[s * 48];
    float ds[16], bs[16];
    *(float4*)&ds[0]  = *(const float4*)&rowp[0];
    *(float4*)&ds[4]  = *(const float4*)&rowp[4];
    *(float4*)&ds[8]  = *(const float4*)&rowp[8];
    *(float4*)&ds[12] = *(const float4*)&rowp[12];
    *(float4*)&bs[0]  = *(const float4*)&rowp[16];
    *(float4*)&bs[4]  = *(const float4*)&rowp[20];
    *(float4*)&bs[8]  = *(const float4*)&rowp[24];
    *(float4*)&bs[12] = *(const float4*)&rowp[28];
    float dtr = dpbv;
    #pragma unroll
    for (int n = 0; n < NST_; n++) dtr += ds[n] * dpw[n];
    float dtv = softplus_f(dtr);
    float u = b2f(sU[s * 512 + d]);
    float du = dtv * u;
    #pragma unroll
    for (int n = 0; n < NST_; n++) {
      float dA = exp2_i(dtv * a2[n]);
      ap[n] *= dA;
      hl[n] = dA * hl[n] + du * bs[n];
    }
  }
  size_t o = ((size_t)((b * NC_ + c) * DIN_ + d)) * NST_;
  #pragma unroll
  for (int q = 0; q < 4; q++) {
    *(float4*)&chA[o + q * 4] = *(const float4*)&ap[q * 4];
    *(float4*)&chH[o + q * 4] = *(const float4*)&hl[q * 4];
  }
}

__global__ __launch_bounds__(256) void scan_mid_k(float* __restrict__ chA, const float* __restrict__ chH)
{
  int idx = blockIdx.x * 256 + threadIdx.x;
  int b = idx >> 13;
  int dn = idx & 8191;
  float h = 0.f;
  #pragma unroll 4
  for (int c = 0; c < NC_; c++) {
    size_t o = ((size_t)(b * NC_ + c)) * 8192 + dn;
    float ap = chA[o];
    float hl = chH[o];
    chA[o] = h;
    h = ap * h + hl;
  }
}

__global__ __launch_bounds__(512) void scan_passC_k(
    const u16* __restrict__ zb,       // z bf16 [B*T,512]
    const u16* __restrict__ xcb,      // u bf16
    const float* __restrict__ xdbc,   // dt-in 0:16, B 16:32, C 32:48
    const float* __restrict__ dpW, const float* __restrict__ dpb,
    const float* __restrict__ Alog,
    const float* __restrict__ chA,    // h_in
    const float* __restrict__ Dv,
    u16* __restrict__ yzb)            // [B*T,512] bf16
{
  __shared__ float sDBC[TC_ * 48];
  __shared__ u16 sU[TC_ * 512];
  __shared__ u16 sZ[TC_ * 512];
  int c = blockIdx.x, b = blockIdx.y, d = threadIdx.x;
  int w = d >> 6;
  size_t base_row = (size_t)(b * T_ + c * TC_);

  if (d < 384) async16(xdbc + base_row * 48 + d * 4, &sDBC[w * 256]);
  #pragma unroll
  for (int i = 0; i < 4; i++)
    async16(xcb + base_row * 512 + i * 4096 + d * 8, &sU[i * 4096 + w * 512]);
  #pragma unroll
  for (int i = 0; i < 4; i++)
    async16(zb + base_row * 512 + i * 4096 + d * 8, &sZ[i * 4096 + w * 512]);

  float a2[NST_], dpw[NST_], hs[NST_];
  size_t ho = ((size_t)((b * NC_ + c) * DIN_ + d)) * NST_;
  #pragma unroll
  for (int q = 0; q < 4; q++) *(float4*)&hs[q * 4] = *(const float4*)&chA[ho + q * 4];
  #pragma unroll
  for (int n = 0; n < NST_; n++) {
    a2[n] = -exp2_i(Alog[d * NST_ + n] * LOG2E) * LOG2E;
    dpw[n] = dpW[d * NST_ + n];
  }
  float dpbv = dpb[d];
  float dv = Dv[d];
  __syncthreads();

  for (int s = 0; s < TC_; s++) {
    const float* rowp = &sDBC[s * 48];
    float ds[16], bs[16], cs[16];
    *(float4*)&ds[0]  = *(const float4*)&rowp[0];
    *(float4*)&ds[4]  = *(const float4*)&rowp[4];
    *(float4*)&ds[8]  = *(const float4*)&rowp[8];
    *(float4*)&ds[12] = *(const float4*)&rowp[12];
    *(float4*)&bs[0]  = *(const float4*)&rowp[16];
    *(float4*)&bs[4]  = *(const float4*)&rowp[20];
    *(float4*)&bs[8]  = *(const float4*)&rowp[24];
    *(float4*)&bs[12] = *(const float4*)&rowp[28];
    *(float4*)&cs[0]  = *(const float4*)&rowp[32];
    *(float4*)&cs[4]  = *(const float4*)&rowp[36];
    *(float4*)&cs[8]  = *(const float4*)&rowp[40];
    *(float4*)&cs[12] = *(const float4*)&rowp[44];
    float dtr = dpbv;
    #pragma unroll
    for (int n = 0; n < NST_; n++) dtr += ds[n] * dpw[n];
    float dtv = softplus_f(dtr);
    float u = b2f(sU[s * 512 + d]);
    float z = b2f(sZ[s * 512 + d]);
    float du = dtv * u;
    float y = 0.f;
    #pragma unroll
    for (int n = 0; n < NST_; n++) {
      float dA = exp2_i(dtv * a2[n]);
      hs[n] = dA * hs[n] + du * bs[n];
      y += hs[n] * cs[n];
    }
    y += u * dv;
    yzb[(base_row + s) * DIN_ + d] = f2b(y * silu_f(z));
  }
}

// -------------------- pooling + head --------------------
__global__ __launch_bounds__(256) void pool_partial_k(const u16* __restrict__ xn, float* __restrict__ poolP)
{
  int b = blockIdx.x, tc = blockIdx.y, j = threadIdx.x;
  float s = 0.f;
  int t0 = tc * 256;
  #pragma unroll 4
  for (int tt = 0; tt < 256; tt++)
    s += b2f(xn[((size_t)(b * T_ + t0 + tt)) * HID_ + j]);
  poolP[(b * 8 + tc) * HID_ + j] = s;
}

__global__ __launch_bounds__(256) void head_k(
    const float* __restrict__ poolP,
    const float* __restrict__ denW, const float* __restrict__ denb,
    const float* __restrict__ hdW, const float* __restrict__ hdb,
    float* __restrict__ out)
{
  int b = blockIdx.x, j = threadIdx.x;
  float p = 0.f;
  #pragma unroll
  for (int tc = 0; tc < 8; tc++) p += poolP[(b * 8 + tc) * HID_ + j];
  p *= (1.f / 2048.f);
  __shared__ float pl[256], zs[256];
  pl[j] = p;
  __syncthreads();
  float acc = denb[j];
  #pragma unroll 8
  for (int k = 0; k < 256; k++) acc += pl[k] * denW[j * 256 + k];
  zs[j] = fmaxf(acc, 0.f);
  __syncthreads();
  if (j < 2) {
    float o = hdb[j];
    for (int k = 0; k < 256; k++) o += zs[k] * hdW[j * 256 + k];
    out[b * 2 + j] = o;
  }
}

// -------------------- host --------------------
extern "C" void kernel_launch(void* const* d_in, const int* in_sizes, int n_in,
                              void* d_out, int out_size, void* d_ws, size_t ws_size,
                              hipStream_t stream)
{
  const float* tsd   = (const float*)d_in[0];
  const float* stat  = (const float*)d_in[1];
  const float* ta    = (const float*)d_in[2];
  const float* tsW   = (const float*)d_in[3];
  const float* tsb   = (const float*)d_in[4];
  const float* t2vw  = (const float*)d_in[5];
  const float* t2vb  = (const float*)d_in[6];
  const float* timeW = (const float*)d_in[7];
  const float* timeb = (const float*)d_in[8];
  const float* statW = (const float*)d_in[9];
  const float* statb = (const float*)d_in[10];
  const float* lng   = (const float*)d_in[11];
  const float* lnb   = (const float*)d_in[12];
  const float* normw = (const float*)d_in[13];
  const float* ipW   = (const float*)d_in[14];
  const float* convW = (const float*)d_in[15];
  const float* convb = (const float*)d_in[16];
  const float* xpW   = (const float*)d_in[17];
  const float* dpW   = (const float*)d_in[18];
  const float* dpb   = (const float*)d_in[19];
  const float* Alog  = (const float*)d_in[20];
  const float* Dsk   = (const float*)d_in[21];
  const float* opW   = (const float*)d_in[22];
  const float* normf = (const float*)d_in[23];
  const float* denW  = (const float*)d_in[24];
  const float* denb  = (const float*)d_in[25];
  const float* hdW   = (const float*)d_in[26];
  const float* hdb   = (const float*)d_in[27];
  float* out = (float*)d_out;

  float* ws = (float*)d_ws;
  float* h    = ws;  ws += (size_t)B_ * T_ * HID_;          // 16.8 MB
  float* xdbc = ws;  ws += (size_t)B_ * T_ * 48;            // 3.1 MB
  float* chA  = ws;  ws += (size_t)B_ * NC_ * DIN_ * NST_;  // 16.8 MB
  float* chH  = ws;  ws += (size_t)B_ * NC_ * DIN_ * NST_;  // 16.8 MB
  float* poolP= ws;  ws += (size_t)B_ * 8 * HID_;
  u16* xi_b   = (u16*)ws;  ws += (size_t)B_ * T_ * DIN_ / 2;  // 16.8 MB
  u16* z_b    = (u16*)ws;  ws += (size_t)B_ * T_ * DIN_ / 2;  // 16.8 MB
  u16* xn_b   = (u16*)ws;  ws += (size_t)B_ * T_ * HID_ / 2;  // 8.4 MB
  u16* xcb    = (u16*)ws;  ws += (size_t)B_ * T_ * DIN_ / 2;  // 16.8 MB
  u16* yz_b   = (u16*)ws;  ws += (size_t)B_ * T_ * DIN_ / 2;  // 16.8 MB
  u16* wipb   = (u16*)ws;  ws += (size_t)NL_ * 1024 * HID_ / 2;
  u16* wopb   = (u16*)ws;  ws += (size_t)NL_ * HID_ * DIN_ / 2;
  u16* wxpb   = (u16*)ws;  ws += (size_t)NL_ * 48 * DIN_ / 2;

  const int ROWS = B_ * T_;   // 16384

  {
    int nip = NL_ * 1024 * HID_;
    int nop = NL_ * HID_ * DIN_;
    int nxp = NL_ * 48 * DIN_;
    f2b_k<<<nip / 1024, 256, 0, stream>>>(ipW, wipb, nip);
    f2b_k<<<nop / 1024, 256, 0, stream>>>(opW, wopb, nop);
    f2b_k<<<nxp / 1024, 256, 0, stream>>>(xpW, wxpb, nxp);
  }

  embed_ln_k<<<512, 256, 0, stream>>>(tsd, stat, ta, tsW, tsb, t2vw, t2vb,
                                      timeW, timeb, statW, statb, lng, lnb, h);

  for (int i = 0; i < NL_; i++) {
    const u16* wipbi = wipb + (size_t)i * 1024 * HID_;
    const u16* wopbi = wopb + (size_t)i * HID_ * DIN_;
    const u16* wxpbi = wxpb + (size_t)i * 48 * DIN_;
    const float* dpWi = dpW + (size_t)i * DIN_ * RANK_;
    const float* dpbi = dpb + (size_t)i * DIN_;
    const float* Ali  = Alog + (size_t)i * DIN_ * NST_;

    rmsnorm_k<<<ROWS, 256, 0, stream>>>(h, normw + i * HID_, xn_b);
    // in_proj split: xi half and z half, each [16384,512,256] -> contiguous
    mgemm_k<false, true><<<dim3(ROWS / 128, 4), 256, 0, stream>>>(
        xn_b, HID_, wipbi, HID_, xi_b, 512, HID_);
    mgemm_k<false, true><<<dim3(ROWS / 128, 4), 256, 0, stream>>>(
        xn_b, HID_, wipbi + (size_t)512 * HID_, HID_, z_b, 512, HID_);
    // conv + silu -> xcb bf16
    conv_silu_k<<<ROWS * 64 / 256, 256, 0, stream>>>(xi_b, convW + i * DIN_ * 4, convb + i * DIN_, xcb);
    // x_proj MFMA -> xdbc f32 [16384,48]
    xproj_k<<<ROWS / 64, 256, 0, stream>>>(xcb, wxpbi, xdbc);
    // chunked selective scan (dt fused) -> yz bf16
    scan_passA_k<<<dim3(NC_, B_), DIN_, 0, stream>>>(xcb, xdbc, dpWi, dpbi, Ali, chA, chH);
    scan_mid_k<<<B_ * DIN_ * NST_ / 256, 256, 0, stream>>>(chA, chH);
    scan_passC_k<<<dim3(NC_, B_), DIN_, 0, stream>>>(z_b, xcb, xdbc, dpWi, dpbi, Ali, chA,
                                                     Dsk + i * DIN_, yz_b);
    // out_proj + residual -> h f32
    mgemm_k<true, false><<<dim3(ROWS / 128, HID_ / 128), 256, 0, stream>>>(
        yz_b, DIN_, wopbi, DIN_, h, HID_, DIN_);
  }

  rmsnorm_k<<<ROWS, 256, 0, stream>>>(h, normf, xn_b);
  pool_partial_k<<<dim3(B_, 8), 256, 0, stream>>>(xn_b, poolP);
  head_k<<<B_, 256, 0, stream>>>(poolP, denW, denb, hdW, hdb, out);
}